// Round 6
// baseline (880.519 us; speedup 1.0000x reference)
//
#include <hip/hip_runtime.h>
#include <math.h>

#define D_MODEL 512
#define NHEADS 8
#define DK 64
#define BATCH 2
#define SEQ 4096
#define NSPLIT 4
#define NIT 16          // 1024 keys per split / 64-key tiles
// log2(e)/8 folded into Q projection: scores in log2 domain, softmax uses exp2.
#define ATTN_SCALE 0.18033688011112043f

typedef _Float16 half8 __attribute__((ext_vector_type(8)));
typedef _Float16 half4 __attribute__((ext_vector_type(4)));
typedef __fp16 pkhalf2 __attribute__((ext_vector_type(2)));
typedef float f32x4 __attribute__((ext_vector_type(4)));
typedef float f32x16 __attribute__((ext_vector_type(16)));

union Pk8 { _Float16 h[8]; uint4 u; };
union Pk4 { _Float16 h[4]; uint2 u; };
union Pkz { pkhalf2 h2[2]; uint2 u; };
union Un4 { uint2 u; _Float16 h[4]; };
union PFu { unsigned int u[4]; half8 h8; };

#if __has_builtin(__builtin_amdgcn_exp2f)
#define EXP2F __builtin_amdgcn_exp2f
#else
#define EXP2F exp2f
#endif

#define MFMA16(a, b, c) __builtin_amdgcn_mfma_f32_16x16x32_f16((a), (b), (c), 0, 0, 0)
#define MFMA32(a, b, c) __builtin_amdgcn_mfma_f32_32x32x16_f16((a), (b), (c), 0, 0, 0)

// in-place cross-half lane exchange: x[32..63] <- y_old[0..31], y[0..31] <- x_old[32..63]
#define PLSWAP(x, y) asm volatile("v_permlane32_swap_b32 %0, %1" : "+v"(x), "+v"(y))

__device__ __forceinline__ unsigned int cvtpk(float a, float b) {
    union { pkhalf2 h; unsigned int u; } u_;
    u_.h = __builtin_amdgcn_cvt_pkrtz(a, b);
    return u_.u;
}

__device__ __forceinline__ void gload_lds16(const _Float16* g, _Float16* l) {
    __builtin_amdgcn_global_load_lds(
        (const __attribute__((address_space(1))) void*)g,
        (__attribute__((address_space(3))) void*)l, 16, 0, 0);
}

// ============================================================================
// prep: fp32->fp16 for 3 activations + 4 weight hi-planes.
// ============================================================================
#define ABLK 4096
#define WBLK 256
__global__ __launch_bounds__(256)
void prep(const float* __restrict__ aq, const float* __restrict__ ak,
          const float* __restrict__ av,
          const float* __restrict__ wq, const float* __restrict__ wk,
          const float* __restrict__ wv, const float* __restrict__ wo,
          _Float16* __restrict__ dq, _Float16* __restrict__ dk,
          _Float16* __restrict__ dv,
          _Float16* __restrict__ hq, _Float16* __restrict__ hk,
          _Float16* __restrict__ hv, _Float16* __restrict__ ho) {
    int gid = blockIdx.x;
    const float* src;
    _Float16* hi;
    if (gid < 3 * ABLK) {
        const int w = gid / ABLK;
        gid -= w * ABLK;
        src = w == 0 ? aq : (w == 1 ? ak : av);
        hi  = w == 0 ? dq : (w == 1 ? dk : dv);
    } else {
        int g = gid - 3 * ABLK;
        const int w = g / WBLK;
        gid = g - w * WBLK;
        src = w == 0 ? wq : (w == 1 ? wk : (w == 2 ? wv : wo));
        hi  = w == 0 ? hq : (w == 1 ? hk : (w == 2 ? hv : ho));
    }
    const int i = (gid * 256 + threadIdx.x) * 4;
    float4 v = *(const float4*)(src + i);
    Pkz h;
    h.h2[0] = __builtin_amdgcn_cvt_pkrtz(v.x, v.y);
    h.h2[1] = __builtin_amdgcn_cvt_pkrtz(v.z, v.w);
    *(uint2*)(hi + i) = h.u;
}

// ============================================================================
// QKV projection GEMM (unchanged): double-buffered DMA, 128x128, BK=64.
// ============================================================================
__global__ __launch_bounds__(256)
void gemm_qkv(const _Float16* __restrict__ Aq, const _Float16* __restrict__ Ak,
              const _Float16* __restrict__ Av,
              const _Float16* __restrict__ Whq, const _Float16* __restrict__ Whk,
              const _Float16* __restrict__ Whv,
              const float* __restrict__ bq, const float* __restrict__ bk,
              const float* __restrict__ bv,
              _Float16* __restrict__ Qf, _Float16* __restrict__ Kf,
              _Float16* __restrict__ Vtf) {
    const int z = blockIdx.z;
    const _Float16* A    = z == 0 ? Aq  : (z == 1 ? Ak  : Av);
    const _Float16* Wh   = z == 0 ? Whq : (z == 1 ? Whk : Whv);
    const float*    bias = z == 0 ? bq  : (z == 1 ? bk  : bv);

    __shared__ __align__(16) _Float16 sA[2][128 * 64];
    __shared__ __align__(16) _Float16 sW[2][128 * 64];

    const int t    = threadIdx.x;
    const int lane = t & 63, wave = t >> 6;
    const int col  = lane & 15, quad = lane >> 4;
    const int wm   = (wave & 1) * 64, wn = (wave >> 1) * 64;
    const int m0   = blockIdx.y * 128, n0 = blockIdx.x * 128;

    const int subrow = lane >> 3;
    const int schunk = ((lane & 7) ^ subrow) * 8;

    #define STAGE_AW(K0, BUF)                                                        \
        do {                                                                          \
            _Pragma("unroll")                                                         \
            for (int j = 0; j < 4; ++j) {                                             \
                const int rw = wave * 32 + j * 8;                                     \
                gload_lds16(A  + (size_t)(m0 + rw + subrow) * 512 + (K0) + schunk,    \
                            &sA[BUF][rw * 64]);                                       \
                gload_lds16(Wh + (size_t)(n0 + rw + subrow) * 512 + (K0) + schunk,    \
                            &sW[BUF][rw * 64]);                                       \
            }                                                                         \
        } while (0)

    f32x4 acc[4][4] = {};

    STAGE_AW(0, 0);
    for (int ck = 0; ck < 8; ++ck) {
        const int cur = ck & 1;
        __syncthreads();
        if (ck + 1 < 8) STAGE_AW((ck + 1) * 64, cur ^ 1);

        #pragma unroll
        for (int kc = 0; kc < 2; ++kc) {
            const int pos = ((kc * 4 + quad) ^ (col & 7)) * 8;
            half8 af[4], wf[4];
            #pragma unroll
            for (int mt = 0; mt < 4; ++mt)
                af[mt] = *(const half8*)&sA[cur][(wm + mt * 16 + col) * 64 + pos];
            #pragma unroll
            for (int nt = 0; nt < 4; ++nt)
                wf[nt] = *(const half8*)&sW[cur][(wn + nt * 16 + col) * 64 + pos];
            #pragma unroll
            for (int mt = 0; mt < 4; ++mt)
                #pragma unroll
                for (int nt = 0; nt < 4; ++nt)
                    acc[mt][nt] = MFMA16(af[mt], wf[nt], acc[mt][nt]);
        }
    }

    float bv4[4];
    #pragma unroll
    for (int nt = 0; nt < 4; ++nt) bv4[nt] = bias[n0 + wn + nt * 16 + col];

    if (z < 2) {
        _Float16* Out = z == 0 ? Qf : Kf;
        const float alpha = z == 0 ? ATTN_SCALE : 1.0f;
        #pragma unroll
        for (int mt = 0; mt < 4; ++mt) {
            const int m = m0 + wm + mt * 16 + quad * 4;
            #pragma unroll
            for (int nt = 0; nt < 4; ++nt) {
                const int n = n0 + wn + nt * 16 + col;
                #pragma unroll
                for (int r = 0; r < 4; ++r)
                    Out[(size_t)(m + r) * 512 + n] = (_Float16)((acc[mt][nt][r] + bv4[nt]) * alpha);
            }
        }
    } else {
        #pragma unroll
        for (int mt = 0; mt < 4; ++mt) {
            const int m = m0 + wm + mt * 16 + quad * 4;
            const int b = m >> 12, s = m & (SEQ - 1);
            #pragma unroll
            for (int nt = 0; nt < 4; ++nt) {
                const int n = n0 + wn + nt * 16 + col;
                const int hh = n >> 6, d = n & (DK - 1);
                Pk4 p;
                #pragma unroll
                for (int r = 0; r < 4; ++r)
                    p.h[r] = (_Float16)(acc[mt][nt][r] + bv4[nt]);
                *(uint2*)&Vtf[((size_t)((b * NHEADS + hh) * DK + d)) * SEQ + s] = p.u;
            }
        }
    }
}

// ============================================================================
// Flash attention, K-split x4, stream-major grid (XCD = head).
// r18: r5's per-work efficiency + r4's parallelism, minus the extra MFMA.
//  - 64 q/wave kept (K/V frags read once, feed both q-tiles; LDS traffic and
//    conflicts stay halved).
//  - ones-MFMA dropped: l accumulated by VALU adds inside the exp loop
//    (MFMA work 40 -> 32 per wave-iter, a -20% cut of the largest pipe).
//  - K-split x4 (NIT=16): 4096 waves = 4 waves/SIMD from independent blocks
//    -> cross-wave MFMA/VALU phase overlap restored (r5 had only 2).
//  - grid x = h + 8*(b*4+sp): XCD = h preserved. 1024 blocks = 4/CU,
//    LDS 128 KB/CU, launch_bounds(256,4).
//  - merge is 4-way flash-combine; Op2/Op3 reuse dead activation planes.
// ============================================================================
__global__ __launch_bounds__(256, 4)
void attn_mfma(const _Float16* __restrict__ Qf, const _Float16* __restrict__ Kf,
               const _Float16* __restrict__ Vtf,
               _Float16* __restrict__ Op0, _Float16* __restrict__ Op1,
               _Float16* __restrict__ Op2, _Float16* __restrict__ Op3,
               float2* __restrict__ Ml) {
    __shared__ __align__(16) _Float16 sK[2][64 * 64];
    __shared__ __align__(16) _Float16 sV[2][64 * 64];

    const int t    = threadIdx.x;
    const int lane = t & 63;
    const int wave = t >> 6;
    const int l31  = lane & 31;
    const int g    = lane >> 5;

    // stream-major grid: x = h + 8*(b*4+sp)  (=> XCD = linear%8 = h), y = qblock
    const int strm = blockIdx.x;
    const int h  = strm & (NHEADS - 1);
    const int z  = strm >> 3;
    const int b  = z >> 2;
    const int sp = z & 3;
    const int q0 = blockIdx.y * 256;
    const int kBase = sp * (SEQ / NSPLIT);

    const size_t rowBase = (size_t)b * SEQ;
    const size_t vBase   = ((size_t)(b * NHEADS + h)) * DK * SEQ;

    // ---- DMA pointers; issue K/V tile 0 immediately ----
    const int subrow = lane >> 3;
    const int schunk = ((lane & 7) ^ subrow) * 8;
    const _Float16* kP[2];
    const _Float16* vP[2];
    #pragma unroll
    for (int j = 0; j < 2; ++j) {
        const int rw = wave * 16 + j * 8;
        kP[j] = Kf + (rowBase + kBase + rw + subrow) * 512 + h * 64 + schunk;
        vP[j] = Vtf + vBase + (size_t)(rw + subrow) * SEQ + kBase + schunk;
        gload_lds16(kP[j], &sK[0][rw * 64]);
        gload_lds16(vP[j], &sV[0][rw * 64]);
        kP[j] += 64 * 512;
        vP[j] += 64;
    }

    // ---- Q fragments direct from global: qf[qt][kc] ----
    half8 qf[2][4];
    #pragma unroll
    for (int qt = 0; qt < 2; ++qt)
        #pragma unroll
        for (int kc = 0; kc < 4; ++kc)
            qf[qt][kc] = *(const half8*)(Qf +
                (rowBase + q0 + wave * 64 + qt * 32 + l31) * 512 +
                h * 64 + kc * 16 + g * 8);

    const int rs = l31 & 7;   // row-XOR swizzle key for K/V LDS reads

    float m_r = 0.0f;
    f32x16 nbv = {};          // -m_r broadcast; all-zero in the common path
    float l_r[2] = { 0.0f, 0.0f };
    f32x16 of[2][2] = {};     // [qt][dt]

    for (int itp = 0; itp < NIT; itp += 2) {
        #pragma unroll
        for (int cur = 0; cur < 2; ++cur) {     // compile-time cur
            const int it = itp + cur;
            __syncthreads();   // drains DMA(it) + frees buf cur^1
            if (it + 1 < NIT) {
                #pragma unroll
                for (int j = 0; j < 2; ++j) {
                    const int rw = wave * 16 + j * 8;
                    gload_lds16(kP[j], &sK[cur ^ 1][rw * 64]);
                    gload_lds16(vP[j], &sV[cur ^ 1][rw * 64]);
                    kP[j] += 64 * 512;
                    vP[j] += 64;
                }
            }

            #pragma unroll
            for (int kt = 0; kt < 2; ++kt) {
                // ---- S^T = K · Q^T : 8 MFMA, K frag shared across qt ----
                f32x16 sf0, sf1;
                __builtin_amdgcn_s_setprio(1);
                #pragma unroll
                for (int kc = 0; kc < 4; ++kc) {
                    const int pos = ((kc * 2 + g) ^ rs) * 8;
                    half8 kf = *(const half8*)&sK[cur][(kt * 32 + l31) * 64 + pos];
                    sf0 = MFMA32(kf, qf[0][kc], kc == 0 ? nbv : sf0);
                    sf1 = MFMA32(kf, qf[1][kc], kc == 0 ? nbv : sf1);
                }
                __builtin_amdgcn_s_setprio(0);

                // ---- softmax in-register; l accumulated on VALU ----
                float lrs0 = 0.0f, lrs1 = 0.0f;
                #pragma unroll
                for (int j2 = 0; j2 < 16; ++j2) {
                    sf0[j2] = EXP2F(sf0[j2]);  lrs0 += sf0[j2];
                    sf1[j2] = EXP2F(sf1[j2]);  lrs1 += sf1[j2];
                }
                l_r[0] += lrs0;
                l_r[1] += lrs1;

                // ---- P^T -> B frags: 8 cvt_pk + 4 permlane per qt ----
                PFu pf0[2], pf1[2];
                #define MKPF(P, PF)                                                  \
                    do {                                                             \
                        unsigned int x1 = cvtpk(P[0], P[1]),  x2 = cvtpk(P[2], P[3]);\
                        unsigned int y1 = cvtpk(P[4], P[5]),  y2 = cvtpk(P[6], P[7]);\
                        PLSWAP(x1, y1); PLSWAP(x2, y2);                              \
                        PF[0].u[0] = x1; PF[0].u[1] = x2;                            \
                        PF[0].u[2] = y1; PF[0].u[3] = y2;                            \
                        unsigned int a1 = cvtpk(P[8], P[9]),  a2 = cvtpk(P[10], P[11]);\
                        unsigned int b1 = cvtpk(P[12], P[13]), b2 = cvtpk(P[14], P[15]);\
                        PLSWAP(a1, b1); PLSWAP(a2, b2);                              \
                        PF[1].u[0] = a1; PF[1].u[1] = a2;                            \
                        PF[1].u[2] = b1; PF[1].u[3] = b2;                            \
                    } while (0)
                MKPF(sf0, pf0);
                MKPF(sf1, pf1);
                #undef MKPF

                // ---- O^T += V^T·P^T (V frag shared across qt) ----
                __builtin_amdgcn_s_setprio(1);
                #pragma unroll
                for (int ks2 = 0; ks2 < 2; ++ks2) {
                    const int ks = kt * 2 + ks2;
                    const int pos = ((ks * 2 + g) ^ rs) * 8;
                    half8 v0 = *(const half8*)&sV[cur][l31 * 64 + pos];
                    half8 v1 = *(const half8*)&sV[cur][(32 + l31) * 64 + pos];
                    of[0][0] = MFMA32(v0, pf0[ks2].h8, of[0][0]);
                    of[0][1] = MFMA32(v1, pf0[ks2].h8, of[0][1]);
                    of[1][0] = MFMA32(v0, pf1[ks2].h8, of[1][0]);
                    of[1][1] = MFMA32(v1, pf1[ks2].h8, of[1][1]);
                }
                __builtin_amdgcn_s_setprio(0);
            }

            // ---- rare re-center: running l too large -> scale down 2^-10 ----
            if (__any(fmaxf(l_r[0], l_r[1]) > 1048576.0f)) {
                const float al = 0.0009765625f;   // 2^-10
                #pragma unroll
                for (int qt = 0; qt < 2; ++qt) {
                    l_r[qt] *= al;
                    #pragma unroll
                    for (int j2 = 0; j2 < 16; ++j2) {
                        of[qt][0][j2] *= al;
                        of[qt][1][j2] *= al;
                    }
                }
                m_r += 10.0f;
                #pragma unroll
                for (int j2 = 0; j2 < 16; ++j2) nbv[j2] = -m_r;
            }
        }
    }

    // ---- finalize: per-split normalized O (fp16) + (m, l) ----
    _Float16* Opx = sp == 0 ? Op0 : (sp == 1 ? Op1 : (sp == 2 ? Op2 : Op3));
    #pragma unroll
    for (int qt = 0; qt < 2; ++qt) {
        const float l = l_r[qt] + __shfl_xor(l_r[qt], 32);
        const float inv = 1.0f / l;
        const int q = q0 + wave * 64 + qt * 32 + l31;
        const size_t R = rowBase + q;
        #pragma unroll
        for (int dt = 0; dt < 2; ++dt) {
            #pragma unroll
            for (int m4 = 0; m4 < 4; ++m4) {
                const int d0 = dt * 32 + 8 * m4 + 4 * g;
                Pkz z2;
                z2.h2[0] = __builtin_amdgcn_cvt_pkrtz(of[qt][dt][4 * m4 + 0] * inv,
                                                      of[qt][dt][4 * m4 + 1] * inv);
                z2.h2[1] = __builtin_amdgcn_cvt_pkrtz(of[qt][dt][4 * m4 + 2] * inv,
                                                      of[qt][dt][4 * m4 + 3] * inv);
                *(uint2*)(Opx + R * 512 + h * 64 + d0) = z2.u;
            }
        }
        if (lane < 32)
            Ml[((size_t)sp * BATCH * SEQ + R) * NHEADS + h] = make_float2(m_r, l);
    }
}

// ============================================================================
// attn_merge: 4-way flash-combine of the K-split partials -> Oh.
// (Op3 aliases Oh: each thread reads all inputs before writing.)
// ============================================================================
__global__ __launch_bounds__(256)
void attn_merge(const _Float16* __restrict__ Op0, const _Float16* __restrict__ Op1,
                const _Float16* __restrict__ Op2, const _Float16* __restrict__ Op3,
                const float2* __restrict__ Ml, _Float16* __restrict__ Oh) {
    const int i4 = (blockIdx.x * 256 + threadIdx.x) * 4;
    const int R = i4 >> 9;
    const int c = i4 & 511;
    const int h = c >> 6;

    const size_t mlStride = (size_t)BATCH * SEQ * NHEADS;
    const size_t mlIdx = (size_t)R * NHEADS + h;
    float2 ml0 = Ml[mlIdx];
    float2 ml1 = Ml[mlStride + mlIdx];
    float2 ml2 = Ml[2 * mlStride + mlIdx];
    float2 ml3 = Ml[3 * mlStride + mlIdx];
    const float m = fmaxf(fmaxf(ml0.x, ml1.x), fmaxf(ml2.x, ml3.x));
    float w0 = EXP2F(ml0.x - m) * ml0.y;
    float w1 = EXP2F(ml1.x - m) * ml1.y;
    float w2 = EXP2F(ml2.x - m) * ml2.y;
    float w3 = EXP2F(ml3.x - m) * ml3.y;
    const float inv = 1.0f / (w0 + w1 + w2 + w3);
    w0 *= inv; w1 *= inv; w2 *= inv; w3 *= inv;

    Un4 a, bb, cc, dd;
    a.u  = *(const uint2*)(Op0 + (size_t)R * 512 + c);
    bb.u = *(const uint2*)(Op1 + (size_t)R * 512 + c);
    cc.u = *(const uint2*)(Op2 + (size_t)R * 512 + c);
    dd.u = *(const uint2*)(Op3 + (size_t)R * 512 + c);

    float o0 = w0 * (float)a.h[0] + w1 * (float)bb.h[0] + w2 * (float)cc.h[0] + w3 * (float)dd.h[0];
    float o1 = w0 * (float)a.h[1] + w1 * (float)bb.h[1] + w2 * (float)cc.h[1] + w3 * (float)dd.h[1];
    float o2 = w0 * (float)a.h[2] + w1 * (float)bb.h[2] + w2 * (float)cc.h[2] + w3 * (float)dd.h[2];
    float o3 = w0 * (float)a.h[3] + w1 * (float)bb.h[3] + w2 * (float)cc.h[3] + w3 * (float)dd.h[3];

    Pkz hh;
    hh.h2[0] = __builtin_amdgcn_cvt_pkrtz(o0, o1);
    hh.h2[1] = __builtin_amdgcn_cvt_pkrtz(o2, o3);
    *(uint2*)(Oh + (size_t)R * 512 + c) = hh.u;
}

// ============================================================================
// Output projection: hi-only A and W. Double-buffered DMA. 128x64 block.
// ============================================================================
__global__ __launch_bounds__(256)
void gemm_out(const _Float16* __restrict__ Ah, const _Float16* __restrict__ Wh,
              const float* __restrict__ bias, float* __restrict__ C) {
    __shared__ __align__(16) _Float16 sAh[2][128 * 64];
    __shared__ __align__(16) _Float16 sWh[2][64 * 64];

    const int t    = threadIdx.x;
    const int lane = t & 63, wave = t >> 6;
    const int col  = lane & 15, quad = lane >> 4;
    const int wm   = (wave & 1) * 64, wn = (wave >> 1) * 32;
    const int m0   = blockIdx.y * 128, n0 = blockIdx.x * 64;

    const int subrow = lane >> 3;
    const int schunk = ((lane & 7) ^ subrow) * 8;

    #define STAGE_OUT(K0, BUF)                                                       \
        do {                                                                          \
            _Pragma("unroll")                                                         \
            for (int j = 0; j < 4; ++j) {                                             \
                const int rw = wave * 32 + j * 8;                                     \
                gload_lds16(Ah + (size_t)(m0 + rw + subrow) * 512 + (K0) + schunk,    \
                            &sAh[BUF][rw * 64]);                                      \
            }                                                                         \
            _Pragma("unroll")                                                         \
            for (int j = 0; j < 2; ++j) {                                             \
                const int rw = wave * 16 + j * 8;                                     \
                gload_lds16(Wh + (size_t)(n0 + rw + subrow) * 512 + (K0) + schunk,    \
                            &sWh[BUF][rw * 64]);                                      \
            }                                                                         \
        } while (0)

    f32x4 acc[4][2] = {};

    STAGE_OUT(0, 0);
    for (int ck = 0; ck < 8; ++ck) {
        const int cur = ck & 1;
        __syncthreads();
        if (ck + 1 < 8) STAGE_OUT((ck + 1) * 64, cur ^ 1);

        #pragma unroll
        for (int kc = 0; kc < 2; ++kc) {
            const int pos = ((kc * 4 + quad) ^ (col & 7)) * 8;
            half8 ahf[4], whf[2];
            #pragma unroll
            for (int mt = 0; mt < 4; ++mt)
                ahf[mt] = *(const half8*)&sAh[cur][(wm + mt * 16 + col) * 64 + pos];
            #pragma unroll
            for (int nt = 0; nt < 2; ++nt)
                whf[nt] = *(const half8*)&sWh[cur][(wn + nt * 16 + col) * 64 + pos];
            #pragma unroll
            for (int mt = 0; mt < 4; ++mt)
                #pragma unroll
                for (int nt = 0; nt < 2; ++nt)
                    acc[mt][nt] = MFMA16(ahf[mt], whf[nt], acc[mt][nt]);
        }
    }

    float bv2[2];
    #pragma unroll
    for (int nt = 0; nt < 2; ++nt) bv2[nt] = bias[n0 + wn + nt * 16 + col];

    #pragma unroll
    for (int mt = 0; mt < 4; ++mt) {
        const int m = m0 + wm + mt * 16 + quad * 4;
        #pragma unroll
        for (int nt = 0; nt < 2; ++nt) {
            const int n = n0 + wn + nt * 16 + col;
            #pragma unroll
            for (int r = 0; r < 4; ++r)
                C[(size_t)(m + r) * 512 + n] = acc[mt][nt][r] + bv2[nt];
        }
    }
}

// ============================================================================
extern "C" void kernel_launch(void* const* d_in, const int* in_sizes, int n_in,
                              void* d_out, int out_size, void* d_ws, size_t ws_size,
                              hipStream_t stream) {
    const float* query = (const float*)d_in[0];
    const float* key   = (const float*)d_in[1];
    const float* value = (const float*)d_in[2];
    const float* w_q   = (const float*)d_in[3];
    const float* b_q   = (const float*)d_in[4];
    const float* w_k   = (const float*)d_in[5];
    const float* b_k   = (const float*)d_in[6];
    const float* w_v   = (const float*)d_in[7];
    const float* b_v   = (const float*)d_in[8];
    const float* w_o   = (const float*)d_in[9];
    const float* b_o   = (const float*)d_in[10];
    float* out = (float*)d_out;

    const int WN = D_MODEL * D_MODEL;                     // 262144
    const size_t plane = (size_t)BATCH * SEQ * D_MODEL;   // 4.19M halves

    _Float16* base = (_Float16*)d_ws;
    _Float16* Aq16 = base;                 // -> Op3 / Oh after qkv
    _Float16* Ak16 = Aq16 + plane;         // -> Op2 after qkv
    _Float16* Av16 = Ak16 + plane;         // -> Op0 after qkv
    _Float16* whq  = Av16 + plane;
    _Float16* whk  = whq + WN;
    _Float16* whv  = whk + WN;
    _Float16* who  = whv + WN;
    _Float16* Qf   = who + WN;
    _Float16* Kf   = Qf + plane;
    _Float16* Vtf  = Kf + plane;
    _Float16* Op1  = Vtf + plane;
    float2*   Ml   = (float2*)(Op1 + plane);  // 4*BATCH*SEQ*NHEADS float2 = 2 MB
    _Float16* Oh   = Aq16;
    _Float16* Op0  = Av16;
    _Float16* Op2  = Ak16;
    _Float16* Op3  = Aq16;

    dim3 blk(256);

    hipLaunchKernelGGL(prep, dim3(3 * ABLK + 4 * WBLK), blk, 0, stream,
                       query, key, value, w_q, w_k, w_v, w_o,
                       Aq16, Ak16, Av16, whq, whk, whv, who);

    hipLaunchKernelGGL(gemm_qkv, dim3(D_MODEL / 128, BATCH * SEQ / 128, 3), blk, 0, stream,
                       Aq16, Ak16, Av16,
                       whq, whk, whv,
                       b_q, b_k, b_v, Qf, Kf, Vtf);

    hipLaunchKernelGGL(attn_mfma, dim3(NHEADS * BATCH * NSPLIT, SEQ / 256), blk, 0, stream,
                       Qf, Kf, Vtf, Op0, Op1, Op2, Op3, Ml);

    hipLaunchKernelGGL(attn_merge, dim3(BATCH * SEQ * D_MODEL / 4 / 256), blk, 0, stream,
                       Op0, Op1, Op2, Op3, Ml, Oh);

    hipLaunchKernelGGL(gemm_out, dim3(D_MODEL / 64, BATCH * SEQ / 128), blk, 0, stream,
                       Oh, who, b_o, out);
}

// Round 7
// 246.269 us; speedup vs baseline: 3.5754x; 3.5754x over previous
//
#include <hip/hip_runtime.h>
#include <math.h>

#define D_MODEL 512
#define NHEADS 8
#define DK 64
#define BATCH 2
#define SEQ 4096
#define NSPLIT 4
#define NIT 16          // 1024 keys per split / 64-key tiles
// log2(e)/8 folded into Q projection: scores in log2 domain, softmax uses exp2.
#define ATTN_SCALE 0.18033688011112043f

typedef _Float16 half8 __attribute__((ext_vector_type(8)));
typedef _Float16 half4 __attribute__((ext_vector_type(4)));
typedef __fp16 pkhalf2 __attribute__((ext_vector_type(2)));
typedef float f32x4 __attribute__((ext_vector_type(4)));
typedef float f32x16 __attribute__((ext_vector_type(16)));

union Pk8 { _Float16 h[8]; uint4 u; };
union Pk4 { _Float16 h[4]; uint2 u; };
union Pkz { pkhalf2 h2[2]; uint2 u; };
union Un4 { uint2 u; _Float16 h[4]; };
union PFu { unsigned int u[4]; half8 h8; };

#if __has_builtin(__builtin_amdgcn_exp2f)
#define EXP2F __builtin_amdgcn_exp2f
#else
#define EXP2F exp2f
#endif

#define MFMA16(a, b, c) __builtin_amdgcn_mfma_f32_16x16x32_f16((a), (b), (c), 0, 0, 0)
#define MFMA32(a, b, c) __builtin_amdgcn_mfma_f32_32x32x16_f16((a), (b), (c), 0, 0, 0)

// in-place cross-half lane exchange: x[32..63] <- y_old[0..31], y[0..31] <- x_old[32..63]
#define PLSWAP(x, y) asm volatile("v_permlane32_swap_b32 %0, %1" : "+v"(x), "+v"(y))

__device__ __forceinline__ unsigned int cvtpk(float a, float b) {
    union { pkhalf2 h; unsigned int u; } u_;
    u_.h = __builtin_amdgcn_cvt_pkrtz(a, b);
    return u_.u;
}

__device__ __forceinline__ void gload_lds16(const _Float16* g, _Float16* l) {
    __builtin_amdgcn_global_load_lds(
        (const __attribute__((address_space(1))) void*)g,
        (__attribute__((address_space(3))) void*)l, 16, 0, 0);
}

// ============================================================================
// prep: fp32->fp16 for 3 activations + 4 weight hi-planes.
// ============================================================================
#define ABLK 4096
#define WBLK 256
__global__ __launch_bounds__(256)
void prep(const float* __restrict__ aq, const float* __restrict__ ak,
          const float* __restrict__ av,
          const float* __restrict__ wq, const float* __restrict__ wk,
          const float* __restrict__ wv, const float* __restrict__ wo,
          _Float16* __restrict__ dq, _Float16* __restrict__ dk,
          _Float16* __restrict__ dv,
          _Float16* __restrict__ hq, _Float16* __restrict__ hk,
          _Float16* __restrict__ hv, _Float16* __restrict__ ho) {
    int gid = blockIdx.x;
    const float* src;
    _Float16* hi;
    if (gid < 3 * ABLK) {
        const int w = gid / ABLK;
        gid -= w * ABLK;
        src = w == 0 ? aq : (w == 1 ? ak : av);
        hi  = w == 0 ? dq : (w == 1 ? dk : dv);
    } else {
        int g = gid - 3 * ABLK;
        const int w = g / WBLK;
        gid = g - w * WBLK;
        src = w == 0 ? wq : (w == 1 ? wk : (w == 2 ? wv : wo));
        hi  = w == 0 ? hq : (w == 1 ? hk : (w == 2 ? hv : ho));
    }
    const int i = (gid * 256 + threadIdx.x) * 4;
    float4 v = *(const float4*)(src + i);
    Pkz h;
    h.h2[0] = __builtin_amdgcn_cvt_pkrtz(v.x, v.y);
    h.h2[1] = __builtin_amdgcn_cvt_pkrtz(v.z, v.w);
    *(uint2*)(hi + i) = h.u;
}

// ============================================================================
// QKV projection GEMM (unchanged): double-buffered DMA, 128x128, BK=64.
// ============================================================================
__global__ __launch_bounds__(256)
void gemm_qkv(const _Float16* __restrict__ Aq, const _Float16* __restrict__ Ak,
              const _Float16* __restrict__ Av,
              const _Float16* __restrict__ Whq, const _Float16* __restrict__ Whk,
              const _Float16* __restrict__ Whv,
              const float* __restrict__ bq, const float* __restrict__ bk,
              const float* __restrict__ bv,
              _Float16* __restrict__ Qf, _Float16* __restrict__ Kf,
              _Float16* __restrict__ Vtf) {
    const int z = blockIdx.z;
    const _Float16* A    = z == 0 ? Aq  : (z == 1 ? Ak  : Av);
    const _Float16* Wh   = z == 0 ? Whq : (z == 1 ? Whk : Whv);
    const float*    bias = z == 0 ? bq  : (z == 1 ? bk  : bv);

    __shared__ __align__(16) _Float16 sA[2][128 * 64];
    __shared__ __align__(16) _Float16 sW[2][128 * 64];

    const int t    = threadIdx.x;
    const int lane = t & 63, wave = t >> 6;
    const int col  = lane & 15, quad = lane >> 4;
    const int wm   = (wave & 1) * 64, wn = (wave >> 1) * 64;
    const int m0   = blockIdx.y * 128, n0 = blockIdx.x * 128;

    const int subrow = lane >> 3;
    const int schunk = ((lane & 7) ^ subrow) * 8;

    #define STAGE_AW(K0, BUF)                                                        \
        do {                                                                          \
            _Pragma("unroll")                                                         \
            for (int j = 0; j < 4; ++j) {                                             \
                const int rw = wave * 32 + j * 8;                                     \
                gload_lds16(A  + (size_t)(m0 + rw + subrow) * 512 + (K0) + schunk,    \
                            &sA[BUF][rw * 64]);                                       \
                gload_lds16(Wh + (size_t)(n0 + rw + subrow) * 512 + (K0) + schunk,    \
                            &sW[BUF][rw * 64]);                                       \
            }                                                                         \
        } while (0)

    f32x4 acc[4][4] = {};

    STAGE_AW(0, 0);
    for (int ck = 0; ck < 8; ++ck) {
        const int cur = ck & 1;
        __syncthreads();
        if (ck + 1 < 8) STAGE_AW((ck + 1) * 64, cur ^ 1);

        #pragma unroll
        for (int kc = 0; kc < 2; ++kc) {
            const int pos = ((kc * 4 + quad) ^ (col & 7)) * 8;
            half8 af[4], wf[4];
            #pragma unroll
            for (int mt = 0; mt < 4; ++mt)
                af[mt] = *(const half8*)&sA[cur][(wm + mt * 16 + col) * 64 + pos];
            #pragma unroll
            for (int nt = 0; nt < 4; ++nt)
                wf[nt] = *(const half8*)&sW[cur][(wn + nt * 16 + col) * 64 + pos];
            #pragma unroll
            for (int mt = 0; mt < 4; ++mt)
                #pragma unroll
                for (int nt = 0; nt < 4; ++nt)
                    acc[mt][nt] = MFMA16(af[mt], wf[nt], acc[mt][nt]);
        }
    }

    float bv4[4];
    #pragma unroll
    for (int nt = 0; nt < 4; ++nt) bv4[nt] = bias[n0 + wn + nt * 16 + col];

    if (z < 2) {
        _Float16* Out = z == 0 ? Qf : Kf;
        const float alpha = z == 0 ? ATTN_SCALE : 1.0f;
        #pragma unroll
        for (int mt = 0; mt < 4; ++mt) {
            const int m = m0 + wm + mt * 16 + quad * 4;
            #pragma unroll
            for (int nt = 0; nt < 4; ++nt) {
                const int n = n0 + wn + nt * 16 + col;
                #pragma unroll
                for (int r = 0; r < 4; ++r)
                    Out[(size_t)(m + r) * 512 + n] = (_Float16)((acc[mt][nt][r] + bv4[nt]) * alpha);
            }
        }
    } else {
        #pragma unroll
        for (int mt = 0; mt < 4; ++mt) {
            const int m = m0 + wm + mt * 16 + quad * 4;
            const int b = m >> 12, s = m & (SEQ - 1);
            #pragma unroll
            for (int nt = 0; nt < 4; ++nt) {
                const int n = n0 + wn + nt * 16 + col;
                const int hh = n >> 6, d = n & (DK - 1);
                Pk4 p;
                #pragma unroll
                for (int r = 0; r < 4; ++r)
                    p.h[r] = (_Float16)(acc[mt][nt][r] + bv4[nt]);
                *(uint2*)&Vtf[((size_t)((b * NHEADS + hh) * DK + d)) * SEQ + s] = p.u;
            }
        }
    }
}

// ============================================================================
// Flash attention, K-split x4, stream-major grid (XCD = head).
// r19 == r18 with ONE change: launch_bounds (256,4) -> (256,2).
//  r18's (256,4) imposed a hard 128-VGPR cap; allocator fell to 64 VGPRs and
//  spilled the f32x16 accumulators to scratch (FETCH 1.6 GB, 735 us). The
//  live set is ~110 regs (r17 measured 116 under (256,2)); at ~110 regs the
//  HW fits 4 waves/SIMD anyway (512/110 = 4.6) and LDS (32 KB) fits 5
//  blocks/CU, so the intended 4 blocks/CU occupancy comes naturally, no cap.
// ============================================================================
__global__ __launch_bounds__(256, 2)
void attn_mfma(const _Float16* __restrict__ Qf, const _Float16* __restrict__ Kf,
               const _Float16* __restrict__ Vtf,
               _Float16* __restrict__ Op0, _Float16* __restrict__ Op1,
               _Float16* __restrict__ Op2, _Float16* __restrict__ Op3,
               float2* __restrict__ Ml) {
    __shared__ __align__(16) _Float16 sK[2][64 * 64];
    __shared__ __align__(16) _Float16 sV[2][64 * 64];

    const int t    = threadIdx.x;
    const int lane = t & 63;
    const int wave = t >> 6;
    const int l31  = lane & 31;
    const int g    = lane >> 5;

    // stream-major grid: x = h + 8*(b*4+sp)  (=> XCD = linear%8 = h), y = qblock
    const int strm = blockIdx.x;
    const int h  = strm & (NHEADS - 1);
    const int z  = strm >> 3;
    const int b  = z >> 2;
    const int sp = z & 3;
    const int q0 = blockIdx.y * 256;
    const int kBase = sp * (SEQ / NSPLIT);

    const size_t rowBase = (size_t)b * SEQ;
    const size_t vBase   = ((size_t)(b * NHEADS + h)) * DK * SEQ;

    // ---- DMA pointers; issue K/V tile 0 immediately ----
    const int subrow = lane >> 3;
    const int schunk = ((lane & 7) ^ subrow) * 8;
    const _Float16* kP[2];
    const _Float16* vP[2];
    #pragma unroll
    for (int j = 0; j < 2; ++j) {
        const int rw = wave * 16 + j * 8;
        kP[j] = Kf + (rowBase + kBase + rw + subrow) * 512 + h * 64 + schunk;
        vP[j] = Vtf + vBase + (size_t)(rw + subrow) * SEQ + kBase + schunk;
        gload_lds16(kP[j], &sK[0][rw * 64]);
        gload_lds16(vP[j], &sV[0][rw * 64]);
        kP[j] += 64 * 512;
        vP[j] += 64;
    }

    // ---- Q fragments direct from global: qf[qt][kc] ----
    half8 qf[2][4];
    #pragma unroll
    for (int qt = 0; qt < 2; ++qt)
        #pragma unroll
        for (int kc = 0; kc < 4; ++kc)
            qf[qt][kc] = *(const half8*)(Qf +
                (rowBase + q0 + wave * 64 + qt * 32 + l31) * 512 +
                h * 64 + kc * 16 + g * 8);

    const int rs = l31 & 7;   // row-XOR swizzle key for K/V LDS reads

    float m_r = 0.0f;
    f32x16 nbv = {};          // -m_r broadcast; all-zero in the common path
    float l_r[2] = { 0.0f, 0.0f };
    f32x16 of[2][2] = {};     // [qt][dt]

    for (int itp = 0; itp < NIT; itp += 2) {
        #pragma unroll
        for (int cur = 0; cur < 2; ++cur) {     // compile-time cur
            const int it = itp + cur;
            __syncthreads();   // drains DMA(it) + frees buf cur^1
            if (it + 1 < NIT) {
                #pragma unroll
                for (int j = 0; j < 2; ++j) {
                    const int rw = wave * 16 + j * 8;
                    gload_lds16(kP[j], &sK[cur ^ 1][rw * 64]);
                    gload_lds16(vP[j], &sV[cur ^ 1][rw * 64]);
                    kP[j] += 64 * 512;
                    vP[j] += 64;
                }
            }

            #pragma unroll
            for (int kt = 0; kt < 2; ++kt) {
                // ---- S^T = K · Q^T : 8 MFMA, K frag shared across qt ----
                f32x16 sf0, sf1;
                __builtin_amdgcn_s_setprio(1);
                #pragma unroll
                for (int kc = 0; kc < 4; ++kc) {
                    const int pos = ((kc * 2 + g) ^ rs) * 8;
                    half8 kf = *(const half8*)&sK[cur][(kt * 32 + l31) * 64 + pos];
                    sf0 = MFMA32(kf, qf[0][kc], kc == 0 ? nbv : sf0);
                    sf1 = MFMA32(kf, qf[1][kc], kc == 0 ? nbv : sf1);
                }
                __builtin_amdgcn_s_setprio(0);

                // ---- softmax in-register; l accumulated on VALU ----
                float lrs0 = 0.0f, lrs1 = 0.0f;
                #pragma unroll
                for (int j2 = 0; j2 < 16; ++j2) {
                    sf0[j2] = EXP2F(sf0[j2]);  lrs0 += sf0[j2];
                    sf1[j2] = EXP2F(sf1[j2]);  lrs1 += sf1[j2];
                }
                l_r[0] += lrs0;
                l_r[1] += lrs1;

                // ---- P^T -> B frags: 8 cvt_pk + 4 permlane per qt ----
                PFu pf0[2], pf1[2];
                #define MKPF(P, PF)                                                  \
                    do {                                                             \
                        unsigned int x1 = cvtpk(P[0], P[1]),  x2 = cvtpk(P[2], P[3]);\
                        unsigned int y1 = cvtpk(P[4], P[5]),  y2 = cvtpk(P[6], P[7]);\
                        PLSWAP(x1, y1); PLSWAP(x2, y2);                              \
                        PF[0].u[0] = x1; PF[0].u[1] = x2;                            \
                        PF[0].u[2] = y1; PF[0].u[3] = y2;                            \
                        unsigned int a1 = cvtpk(P[8], P[9]),  a2 = cvtpk(P[10], P[11]);\
                        unsigned int b1 = cvtpk(P[12], P[13]), b2 = cvtpk(P[14], P[15]);\
                        PLSWAP(a1, b1); PLSWAP(a2, b2);                              \
                        PF[1].u[0] = a1; PF[1].u[1] = a2;                            \
                        PF[1].u[2] = b1; PF[1].u[3] = b2;                            \
                    } while (0)
                MKPF(sf0, pf0);
                MKPF(sf1, pf1);
                #undef MKPF

                // ---- O^T += V^T·P^T (V frag shared across qt) ----
                __builtin_amdgcn_s_setprio(1);
                #pragma unroll
                for (int ks2 = 0; ks2 < 2; ++ks2) {
                    const int ks = kt * 2 + ks2;
                    const int pos = ((ks * 2 + g) ^ rs) * 8;
                    half8 v0 = *(const half8*)&sV[cur][l31 * 64 + pos];
                    half8 v1 = *(const half8*)&sV[cur][(32 + l31) * 64 + pos];
                    of[0][0] = MFMA32(v0, pf0[ks2].h8, of[0][0]);
                    of[0][1] = MFMA32(v1, pf0[ks2].h8, of[0][1]);
                    of[1][0] = MFMA32(v0, pf1[ks2].h8, of[1][0]);
                    of[1][1] = MFMA32(v1, pf1[ks2].h8, of[1][1]);
                }
                __builtin_amdgcn_s_setprio(0);
            }

            // ---- rare re-center: running l too large -> scale down 2^-10 ----
            if (__any(fmaxf(l_r[0], l_r[1]) > 1048576.0f)) {
                const float al = 0.0009765625f;   // 2^-10
                #pragma unroll
                for (int qt = 0; qt < 2; ++qt) {
                    l_r[qt] *= al;
                    #pragma unroll
                    for (int j2 = 0; j2 < 16; ++j2) {
                        of[qt][0][j2] *= al;
                        of[qt][1][j2] *= al;
                    }
                }
                m_r += 10.0f;
                #pragma unroll
                for (int j2 = 0; j2 < 16; ++j2) nbv[j2] = -m_r;
            }
        }
    }

    // ---- finalize: per-split normalized O (fp16) + (m, l) ----
    _Float16* Opx = sp == 0 ? Op0 : (sp == 1 ? Op1 : (sp == 2 ? Op2 : Op3));
    #pragma unroll
    for (int qt = 0; qt < 2; ++qt) {
        const float l = l_r[qt] + __shfl_xor(l_r[qt], 32);
        const float inv = 1.0f / l;
        const int q = q0 + wave * 64 + qt * 32 + l31;
        const size_t R = rowBase + q;
        #pragma unroll
        for (int dt = 0; dt < 2; ++dt) {
            #pragma unroll
            for (int m4 = 0; m4 < 4; ++m4) {
                const int d0 = dt * 32 + 8 * m4 + 4 * g;
                Pkz z2;
                z2.h2[0] = __builtin_amdgcn_cvt_pkrtz(of[qt][dt][4 * m4 + 0] * inv,
                                                      of[qt][dt][4 * m4 + 1] * inv);
                z2.h2[1] = __builtin_amdgcn_cvt_pkrtz(of[qt][dt][4 * m4 + 2] * inv,
                                                      of[qt][dt][4 * m4 + 3] * inv);
                *(uint2*)(Opx + R * 512 + h * 64 + d0) = z2.u;
            }
        }
        if (lane < 32)
            Ml[((size_t)sp * BATCH * SEQ + R) * NHEADS + h] = make_float2(m_r, l);
    }
}

// ============================================================================
// attn_merge: 4-way flash-combine of the K-split partials -> Oh.
// (Op3 aliases Oh: each thread reads all inputs before writing.)
// ============================================================================
__global__ __launch_bounds__(256)
void attn_merge(const _Float16* __restrict__ Op0, const _Float16* __restrict__ Op1,
                const _Float16* __restrict__ Op2, const _Float16* __restrict__ Op3,
                const float2* __restrict__ Ml, _Float16* __restrict__ Oh) {
    const int i4 = (blockIdx.x * 256 + threadIdx.x) * 4;
    const int R = i4 >> 9;
    const int c = i4 & 511;
    const int h = c >> 6;

    const size_t mlStride = (size_t)BATCH * SEQ * NHEADS;
    const size_t mlIdx = (size_t)R * NHEADS + h;
    float2 ml0 = Ml[mlIdx];
    float2 ml1 = Ml[mlStride + mlIdx];
    float2 ml2 = Ml[2 * mlStride + mlIdx];
    float2 ml3 = Ml[3 * mlStride + mlIdx];
    const float m = fmaxf(fmaxf(ml0.x, ml1.x), fmaxf(ml2.x, ml3.x));
    float w0 = EXP2F(ml0.x - m) * ml0.y;
    float w1 = EXP2F(ml1.x - m) * ml1.y;
    float w2 = EXP2F(ml2.x - m) * ml2.y;
    float w3 = EXP2F(ml3.x - m) * ml3.y;
    const float inv = 1.0f / (w0 + w1 + w2 + w3);
    w0 *= inv; w1 *= inv; w2 *= inv; w3 *= inv;

    Un4 a, bb, cc, dd;
    a.u  = *(const uint2*)(Op0 + (size_t)R * 512 + c);
    bb.u = *(const uint2*)(Op1 + (size_t)R * 512 + c);
    cc.u = *(const uint2*)(Op2 + (size_t)R * 512 + c);
    dd.u = *(const uint2*)(Op3 + (size_t)R * 512 + c);

    float o0 = w0 * (float)a.h[0] + w1 * (float)bb.h[0] + w2 * (float)cc.h[0] + w3 * (float)dd.h[0];
    float o1 = w0 * (float)a.h[1] + w1 * (float)bb.h[1] + w2 * (float)cc.h[1] + w3 * (float)dd.h[1];
    float o2 = w0 * (float)a.h[2] + w1 * (float)bb.h[2] + w2 * (float)cc.h[2] + w3 * (float)dd.h[2];
    float o3 = w0 * (float)a.h[3] + w1 * (float)bb.h[3] + w2 * (float)cc.h[3] + w3 * (float)dd.h[3];

    Pkz hh;
    hh.h2[0] = __builtin_amdgcn_cvt_pkrtz(o0, o1);
    hh.h2[1] = __builtin_amdgcn_cvt_pkrtz(o2, o3);
    *(uint2*)(Oh + (size_t)R * 512 + c) = hh.u;
}

// ============================================================================
// Output projection: hi-only A and W. Double-buffered DMA. 128x64 block.
// ============================================================================
__global__ __launch_bounds__(256)
void gemm_out(const _Float16* __restrict__ Ah, const _Float16* __restrict__ Wh,
              const float* __restrict__ bias, float* __restrict__ C) {
    __shared__ __align__(16) _Float16 sAh[2][128 * 64];
    __shared__ __align__(16) _Float16 sWh[2][64 * 64];

    const int t    = threadIdx.x;
    const int lane = t & 63, wave = t >> 6;
    const int col  = lane & 15, quad = lane >> 4;
    const int wm   = (wave & 1) * 64, wn = (wave >> 1) * 32;
    const int m0   = blockIdx.y * 128, n0 = blockIdx.x * 64;

    const int subrow = lane >> 3;
    const int schunk = ((lane & 7) ^ subrow) * 8;

    #define STAGE_OUT(K0, BUF)                                                       \
        do {                                                                          \
            _Pragma("unroll")                                                         \
            for (int j = 0; j < 4; ++j) {                                             \
                const int rw = wave * 32 + j * 8;                                     \
                gload_lds16(Ah + (size_t)(m0 + rw + subrow) * 512 + (K0) + schunk,    \
                            &sAh[BUF][rw * 64]);                                      \
            }                                                                         \
            _Pragma("unroll")                                                         \
            for (int j = 0; j < 2; ++j) {                                             \
                const int rw = wave * 16 + j * 8;                                     \
                gload_lds16(Wh + (size_t)(n0 + rw + subrow) * 512 + (K0) + schunk,    \
                            &sWh[BUF][rw * 64]);                                      \
            }                                                                         \
        } while (0)

    f32x4 acc[4][2] = {};

    STAGE_OUT(0, 0);
    for (int ck = 0; ck < 8; ++ck) {
        const int cur = ck & 1;
        __syncthreads();
        if (ck + 1 < 8) STAGE_OUT((ck + 1) * 64, cur ^ 1);

        #pragma unroll
        for (int kc = 0; kc < 2; ++kc) {
            const int pos = ((kc * 4 + quad) ^ (col & 7)) * 8;
            half8 ahf[4], whf[2];
            #pragma unroll
            for (int mt = 0; mt < 4; ++mt)
                ahf[mt] = *(const half8*)&sAh[cur][(wm + mt * 16 + col) * 64 + pos];
            #pragma unroll
            for (int nt = 0; nt < 2; ++nt)
                whf[nt] = *(const half8*)&sWh[cur][(wn + nt * 16 + col) * 64 + pos];
            #pragma unroll
            for (int mt = 0; mt < 4; ++mt)
                #pragma unroll
                for (int nt = 0; nt < 2; ++nt)
                    acc[mt][nt] = MFMA16(ahf[mt], whf[nt], acc[mt][nt]);
        }
    }

    float bv2[2];
    #pragma unroll
    for (int nt = 0; nt < 2; ++nt) bv2[nt] = bias[n0 + wn + nt * 16 + col];

    #pragma unroll
    for (int mt = 0; mt < 4; ++mt) {
        const int m = m0 + wm + mt * 16 + quad * 4;
        #pragma unroll
        for (int nt = 0; nt < 2; ++nt) {
            const int n = n0 + wn + nt * 16 + col;
            #pragma unroll
            for (int r = 0; r < 4; ++r)
                C[(size_t)(m + r) * 512 + n] = acc[mt][nt][r] + bv2[nt];
        }
    }
}

// ============================================================================
extern "C" void kernel_launch(void* const* d_in, const int* in_sizes, int n_in,
                              void* d_out, int out_size, void* d_ws, size_t ws_size,
                              hipStream_t stream) {
    const float* query = (const float*)d_in[0];
    const float* key   = (const float*)d_in[1];
    const float* value = (const float*)d_in[2];
    const float* w_q   = (const float*)d_in[3];
    const float* b_q   = (const float*)d_in[4];
    const float* w_k   = (const float*)d_in[5];
    const float* b_k   = (const float*)d_in[6];
    const float* w_v   = (const float*)d_in[7];
    const float* b_v   = (const float*)d_in[8];
    const float* w_o   = (const float*)d_in[9];
    const float* b_o   = (const float*)d_in[10];
    float* out = (float*)d_out;

    const int WN = D_MODEL * D_MODEL;                     // 262144
    const size_t plane = (size_t)BATCH * SEQ * D_MODEL;   // 4.19M halves

    _Float16* base = (_Float16*)d_ws;
    _Float16* Aq16 = base;                 // -> Op3 / Oh after qkv
    _Float16* Ak16 = Aq16 + plane;         // -> Op2 after qkv
    _Float16* Av16 = Ak16 + plane;         // -> Op0 after qkv
    _Float16* whq  = Av16 + plane;
    _Float16* whk  = whq + WN;
    _Float16* whv  = whk + WN;
    _Float16* who  = whv + WN;
    _Float16* Qf   = who + WN;
    _Float16* Kf   = Qf + plane;
    _Float16* Vtf  = Kf + plane;
    _Float16* Op1  = Vtf + plane;
    float2*   Ml   = (float2*)(Op1 + plane);  // 4*BATCH*SEQ*NHEADS float2 = 2 MB
    _Float16* Oh   = Aq16;
    _Float16* Op0  = Av16;
    _Float16* Op2  = Ak16;
    _Float16* Op3  = Aq16;

    dim3 blk(256);

    hipLaunchKernelGGL(prep, dim3(3 * ABLK + 4 * WBLK), blk, 0, stream,
                       query, key, value, w_q, w_k, w_v, w_o,
                       Aq16, Ak16, Av16, whq, whk, whv, who);

    hipLaunchKernelGGL(gemm_qkv, dim3(D_MODEL / 128, BATCH * SEQ / 128, 3), blk, 0, stream,
                       Aq16, Ak16, Av16,
                       whq, whk, whv,
                       b_q, b_k, b_v, Qf, Kf, Vtf);

    hipLaunchKernelGGL(attn_mfma, dim3(NHEADS * BATCH * NSPLIT, SEQ / 256), blk, 0, stream,
                       Qf, Kf, Vtf, Op0, Op1, Op2, Op3, Ml);

    hipLaunchKernelGGL(attn_merge, dim3(BATCH * SEQ * D_MODEL / 4 / 256), blk, 0, stream,
                       Op0, Op1, Op2, Op3, Ml, Oh);

    hipLaunchKernelGGL(gemm_out, dim3(D_MODEL / 64, BATCH * SEQ / 128), blk, 0, stream,
                       Oh, who, b_o, out);
}

// Round 8
// 240.097 us; speedup vs baseline: 3.6674x; 1.0257x over previous
//
#include <hip/hip_runtime.h>
#include <math.h>

#define D_MODEL 512
#define NHEADS 8
#define DK 64
#define BATCH 2
#define SEQ 4096
#define NSPLIT 2
#define NIT 32          // 2048 keys per split / 64-key tiles
// log2(e)/8 folded into Q projection: scores in log2 domain, softmax uses exp2.
#define ATTN_SCALE 0.18033688011112043f

typedef _Float16 half8 __attribute__((ext_vector_type(8)));
typedef _Float16 half4 __attribute__((ext_vector_type(4)));
typedef __fp16 pkhalf2 __attribute__((ext_vector_type(2)));
typedef float f32x4 __attribute__((ext_vector_type(4)));
typedef float f32x16 __attribute__((ext_vector_type(16)));

union Pk8 { _Float16 h[8]; uint4 u; };
union Pk4 { _Float16 h[4]; uint2 u; };
union Pkz { pkhalf2 h2[2]; uint2 u; };
union Un4 { uint2 u; _Float16 h[4]; };
union PFu { unsigned int u[4]; half8 h8; };

#if __has_builtin(__builtin_amdgcn_exp2f)
#define EXP2F __builtin_amdgcn_exp2f
#else
#define EXP2F exp2f
#endif

#define MFMA16(a, b, c) __builtin_amdgcn_mfma_f32_16x16x32_f16((a), (b), (c), 0, 0, 0)
#define MFMA32(a, b, c) __builtin_amdgcn_mfma_f32_32x32x16_f16((a), (b), (c), 0, 0, 0)

// in-place cross-half lane exchange: x[32..63] <- y_old[0..31], y[0..31] <- x_old[32..63]
#define PLSWAP(x, y) asm volatile("v_permlane32_swap_b32 %0, %1" : "+v"(x), "+v"(y))

__device__ __forceinline__ unsigned int cvtpk(float a, float b) {
    union { pkhalf2 h; unsigned int u; } u_;
    u_.h = __builtin_amdgcn_cvt_pkrtz(a, b);
    return u_.u;
}

__device__ __forceinline__ void gload_lds16(const _Float16* g, _Float16* l) {
    __builtin_amdgcn_global_load_lds(
        (const __attribute__((address_space(1))) void*)g,
        (__attribute__((address_space(3))) void*)l, 16, 0, 0);
}

// ============================================================================
// prep: fp32->fp16 for the 4 weight hi-planes ONLY (activation conversion is
// fused into gemm_qkv's A staging since r8).
// ============================================================================
#define WBLK 256
__global__ __launch_bounds__(256)
void prep(const float* __restrict__ wq, const float* __restrict__ wk,
          const float* __restrict__ wv, const float* __restrict__ wo,
          _Float16* __restrict__ hq, _Float16* __restrict__ hk,
          _Float16* __restrict__ hv, _Float16* __restrict__ ho) {
    int gid = blockIdx.x;
    const int w = gid / WBLK;
    gid -= w * WBLK;
    const float* src = w == 0 ? wq : (w == 1 ? wk : (w == 2 ? wv : wo));
    _Float16* hi     = w == 0 ? hq : (w == 1 ? hk : (w == 2 ? hv : ho));
    const int i = (gid * 256 + threadIdx.x) * 4;
    float4 v = *(const float4*)(src + i);
    Pkz h;
    h.h2[0] = __builtin_amdgcn_cvt_pkrtz(v.x, v.y);
    h.h2[1] = __builtin_amdgcn_cvt_pkrtz(v.z, v.w);
    *(uint2*)(hi + i) = h.u;
}

// ============================================================================
// QKV projection GEMM, r8: A (activations) read DIRECTLY as fp32 and converted
// during reg-staging (float4 x2 -> 4 cvt_pkrtz -> ds_write_b128, same
// XOR-swizzled LDS layout as before). Removes prep's 50 MB fp32 read +
// 25 MB fp16 write + this kernel's 25 MB fp16 re-read. W stays fp16 DMA.
// Loads for tile ck+1 issue right after the barrier and land under the MFMA
// section; the LDS write happens at the end of the phase.
// ============================================================================
__global__ __launch_bounds__(256)
void gemm_qkv(const float* __restrict__ Aq, const float* __restrict__ Ak,
              const float* __restrict__ Av,
              const _Float16* __restrict__ Whq, const _Float16* __restrict__ Whk,
              const _Float16* __restrict__ Whv,
              const float* __restrict__ bq, const float* __restrict__ bk,
              const float* __restrict__ bv,
              _Float16* __restrict__ Qf, _Float16* __restrict__ Kf,
              _Float16* __restrict__ Vtf) {
    const int z = blockIdx.z;
    const float*    A    = z == 0 ? Aq  : (z == 1 ? Ak  : Av);
    const _Float16* Wh   = z == 0 ? Whq : (z == 1 ? Whk : Whv);
    const float*    bias = z == 0 ? bq  : (z == 1 ? bk  : bv);

    __shared__ __align__(16) _Float16 sA[2][128 * 64];
    __shared__ __align__(16) _Float16 sW[2][128 * 64];

    const int t    = threadIdx.x;
    const int lane = t & 63, wave = t >> 6;
    const int col  = lane & 15, quad = lane >> 4;
    const int wm   = (wave & 1) * 64, wn = (wave >> 1) * 64;
    const int m0   = blockIdx.y * 128, n0 = blockIdx.x * 128;

    const int subrow = lane >> 3;
    const int schunk = ((lane & 7) ^ subrow) * 8;

    const float* aBase = A + (size_t)(m0 + wave * 32 + subrow) * 512 + schunk;

    float4 ar[4][2];
    #define LOAD_A(K0)                                                            \
        do {                                                                       \
            _Pragma("unroll")                                                      \
            for (int j = 0; j < 4; ++j) {                                          \
                const float* s = aBase + (size_t)(j * 8) * 512 + (K0);             \
                ar[j][0] = *(const float4*)s;                                      \
                ar[j][1] = *(const float4*)(s + 4);                                \
            }                                                                      \
        } while (0)
    #define WRITE_A(BUF)                                                           \
        do {                                                                       \
            _Pragma("unroll")                                                      \
            for (int j = 0; j < 4; ++j) {                                          \
                uint4 p;                                                           \
                p.x = cvtpk(ar[j][0].x, ar[j][0].y);                               \
                p.y = cvtpk(ar[j][0].z, ar[j][0].w);                               \
                p.z = cvtpk(ar[j][1].x, ar[j][1].y);                               \
                p.w = cvtpk(ar[j][1].z, ar[j][1].w);                               \
                *(uint4*)&sA[BUF][(wave * 32 + j * 8) * 64 + lane * 8] = p;        \
            }                                                                      \
        } while (0)
    #define STAGE_W(K0, BUF)                                                       \
        do {                                                                       \
            _Pragma("unroll")                                                      \
            for (int j = 0; j < 4; ++j) {                                          \
                const int rw = wave * 32 + j * 8;                                  \
                gload_lds16(Wh + (size_t)(n0 + rw + subrow) * 512 + (K0) + schunk, \
                            &sW[BUF][rw * 64]);                                    \
            }                                                                      \
        } while (0)

    f32x4 acc[4][4] = {};

    STAGE_W(0, 0);
    LOAD_A(0);
    WRITE_A(0);

    for (int ck = 0; ck < 8; ++ck) {
        const int cur = ck & 1;
        __syncthreads();
        if (ck + 1 < 8) {
            STAGE_W((ck + 1) * 64, cur ^ 1);
            LOAD_A((ck + 1) * 64);
        }

        #pragma unroll
        for (int kc = 0; kc < 2; ++kc) {
            const int pos = ((kc * 4 + quad) ^ (col & 7)) * 8;
            half8 af[4], wf[4];
            #pragma unroll
            for (int mt = 0; mt < 4; ++mt)
                af[mt] = *(const half8*)&sA[cur][(wm + mt * 16 + col) * 64 + pos];
            #pragma unroll
            for (int nt = 0; nt < 4; ++nt)
                wf[nt] = *(const half8*)&sW[cur][(wn + nt * 16 + col) * 64 + pos];
            #pragma unroll
            for (int mt = 0; mt < 4; ++mt)
                #pragma unroll
                for (int nt = 0; nt < 4; ++nt)
                    acc[mt][nt] = MFMA16(af[mt], wf[nt], acc[mt][nt]);
        }

        if (ck + 1 < 8) WRITE_A(cur ^ 1);
    }

    float bv4[4];
    #pragma unroll
    for (int nt = 0; nt < 4; ++nt) bv4[nt] = bias[n0 + wn + nt * 16 + col];

    if (z < 2) {
        _Float16* Out = z == 0 ? Qf : Kf;
        const float alpha = z == 0 ? ATTN_SCALE : 1.0f;
        #pragma unroll
        for (int mt = 0; mt < 4; ++mt) {
            const int m = m0 + wm + mt * 16 + quad * 4;
            #pragma unroll
            for (int nt = 0; nt < 4; ++nt) {
                const int n = n0 + wn + nt * 16 + col;
                #pragma unroll
                for (int r = 0; r < 4; ++r)
                    Out[(size_t)(m + r) * 512 + n] = (_Float16)((acc[mt][nt][r] + bv4[nt]) * alpha);
            }
        }
    } else {
        #pragma unroll
        for (int mt = 0; mt < 4; ++mt) {
            const int m = m0 + wm + mt * 16 + quad * 4;
            const int b = m >> 12, s = m & (SEQ - 1);
            #pragma unroll
            for (int nt = 0; nt < 4; ++nt) {
                const int n = n0 + wn + nt * 16 + col;
                const int hh = n >> 6, d = n & (DK - 1);
                Pk4 p;
                #pragma unroll
                for (int r = 0; r < 4; ++r)
                    p.h[r] = (_Float16)(acc[mt][nt][r] + bv4[nt]);
                *(uint2*)&Vtf[((size_t)((b * NHEADS + hh) * DK + d)) * SEQ + s] = p.u;
            }
        }
    }
}

// ============================================================================
// Flash attention, K-split x2 (r5 shape — best measured), stream-major grid
// (XCD = head), 64 q/wave, register P via permlane, VALU l (no ones-MFMA:
// 32 MFMA32/wave-iter). LDS 32 KB, 1 barrier/iter, launch_bounds(256,2).
// r7 established occupancy is capped ~2 blocks/CU regardless of grid size, so
// the 2-split (512 blocks) minimizes Q-reload/O-write overhead.
// ============================================================================
__global__ __launch_bounds__(256, 2)
void attn_mfma(const _Float16* __restrict__ Qf, const _Float16* __restrict__ Kf,
               const _Float16* __restrict__ Vtf,
               _Float16* __restrict__ Op0, _Float16* __restrict__ Op1,
               float2* __restrict__ Ml) {
    __shared__ __align__(16) _Float16 sK[2][64 * 64];
    __shared__ __align__(16) _Float16 sV[2][64 * 64];

    const int t    = threadIdx.x;
    const int lane = t & 63;
    const int wave = t >> 6;
    const int l31  = lane & 31;
    const int g    = lane >> 5;

    // stream-major grid: x = h + 8*(b*2+sp)  (=> XCD = linear%8 = h), y = qblock
    const int strm = blockIdx.x;
    const int h  = strm & (NHEADS - 1);
    const int z  = strm >> 3;
    const int b  = z >> 1;
    const int sp = z & 1;
    const int q0 = blockIdx.y * 256;
    const int kBase = sp * (SEQ / NSPLIT);

    const size_t rowBase = (size_t)b * SEQ;
    const size_t vBase   = ((size_t)(b * NHEADS + h)) * DK * SEQ;

    // ---- DMA pointers; issue K/V tile 0 immediately ----
    const int subrow = lane >> 3;
    const int schunk = ((lane & 7) ^ subrow) * 8;
    const _Float16* kP[2];
    const _Float16* vP[2];
    #pragma unroll
    for (int j = 0; j < 2; ++j) {
        const int rw = wave * 16 + j * 8;
        kP[j] = Kf + (rowBase + kBase + rw + subrow) * 512 + h * 64 + schunk;
        vP[j] = Vtf + vBase + (size_t)(rw + subrow) * SEQ + kBase + schunk;
        gload_lds16(kP[j], &sK[0][rw * 64]);
        gload_lds16(vP[j], &sV[0][rw * 64]);
        kP[j] += 64 * 512;
        vP[j] += 64;
    }

    // ---- Q fragments direct from global: qf[qt][kc] ----
    half8 qf[2][4];
    #pragma unroll
    for (int qt = 0; qt < 2; ++qt)
        #pragma unroll
        for (int kc = 0; kc < 4; ++kc)
            qf[qt][kc] = *(const half8*)(Qf +
                (rowBase + q0 + wave * 64 + qt * 32 + l31) * 512 +
                h * 64 + kc * 16 + g * 8);

    const int rs = l31 & 7;   // row-XOR swizzle key for K/V LDS reads

    float m_r = 0.0f;
    f32x16 nbv = {};          // -m_r broadcast; all-zero in the common path
    float l_r[2] = { 0.0f, 0.0f };
    f32x16 of[2][2] = {};     // [qt][dt]

    for (int itp = 0; itp < NIT; itp += 2) {
        #pragma unroll
        for (int cur = 0; cur < 2; ++cur) {     // compile-time cur
            const int it = itp + cur;
            __syncthreads();   // drains DMA(it) + frees buf cur^1
            if (it + 1 < NIT) {
                #pragma unroll
                for (int j = 0; j < 2; ++j) {
                    const int rw = wave * 16 + j * 8;
                    gload_lds16(kP[j], &sK[cur ^ 1][rw * 64]);
                    gload_lds16(vP[j], &sV[cur ^ 1][rw * 64]);
                    kP[j] += 64 * 512;
                    vP[j] += 64;
                }
            }

            #pragma unroll
            for (int kt = 0; kt < 2; ++kt) {
                // ---- S^T = K · Q^T : 8 MFMA, K frag shared across qt ----
                f32x16 sf0, sf1;
                __builtin_amdgcn_s_setprio(1);
                #pragma unroll
                for (int kc = 0; kc < 4; ++kc) {
                    const int pos = ((kc * 2 + g) ^ rs) * 8;
                    half8 kf = *(const half8*)&sK[cur][(kt * 32 + l31) * 64 + pos];
                    sf0 = MFMA32(kf, qf[0][kc], kc == 0 ? nbv : sf0);
                    sf1 = MFMA32(kf, qf[1][kc], kc == 0 ? nbv : sf1);
                }
                __builtin_amdgcn_s_setprio(0);

                // ---- softmax in-register; l accumulated on VALU ----
                float lrs0 = 0.0f, lrs1 = 0.0f;
                #pragma unroll
                for (int j2 = 0; j2 < 16; ++j2) {
                    sf0[j2] = EXP2F(sf0[j2]);  lrs0 += sf0[j2];
                    sf1[j2] = EXP2F(sf1[j2]);  lrs1 += sf1[j2];
                }
                l_r[0] += lrs0;
                l_r[1] += lrs1;

                // ---- P^T -> B frags: 8 cvt_pk + 4 permlane per qt ----
                PFu pf0[2], pf1[2];
                #define MKPF(P, PF)                                                  \
                    do {                                                             \
                        unsigned int x1 = cvtpk(P[0], P[1]),  x2 = cvtpk(P[2], P[3]);\
                        unsigned int y1 = cvtpk(P[4], P[5]),  y2 = cvtpk(P[6], P[7]);\
                        PLSWAP(x1, y1); PLSWAP(x2, y2);                              \
                        PF[0].u[0] = x1; PF[0].u[1] = x2;                            \
                        PF[0].u[2] = y1; PF[0].u[3] = y2;                            \
                        unsigned int a1 = cvtpk(P[8], P[9]),  a2 = cvtpk(P[10], P[11]);\
                        unsigned int b1 = cvtpk(P[12], P[13]), b2 = cvtpk(P[14], P[15]);\
                        PLSWAP(a1, b1); PLSWAP(a2, b2);                              \
                        PF[1].u[0] = a1; PF[1].u[1] = a2;                            \
                        PF[1].u[2] = b1; PF[1].u[3] = b2;                            \
                    } while (0)
                MKPF(sf0, pf0);
                MKPF(sf1, pf1);
                #undef MKPF

                // ---- O^T += V^T·P^T (V frag shared across qt) ----
                __builtin_amdgcn_s_setprio(1);
                #pragma unroll
                for (int ks2 = 0; ks2 < 2; ++ks2) {
                    const int ks = kt * 2 + ks2;
                    const int pos = ((ks * 2 + g) ^ rs) * 8;
                    half8 v0 = *(const half8*)&sV[cur][l31 * 64 + pos];
                    half8 v1 = *(const half8*)&sV[cur][(32 + l31) * 64 + pos];
                    of[0][0] = MFMA32(v0, pf0[ks2].h8, of[0][0]);
                    of[0][1] = MFMA32(v1, pf0[ks2].h8, of[0][1]);
                    of[1][0] = MFMA32(v0, pf1[ks2].h8, of[1][0]);
                    of[1][1] = MFMA32(v1, pf1[ks2].h8, of[1][1]);
                }
                __builtin_amdgcn_s_setprio(0);
            }

            // ---- rare re-center: running l too large -> scale down 2^-10 ----
            if (__any(fmaxf(l_r[0], l_r[1]) > 1048576.0f)) {
                const float al = 0.0009765625f;   // 2^-10
                #pragma unroll
                for (int qt = 0; qt < 2; ++qt) {
                    l_r[qt] *= al;
                    #pragma unroll
                    for (int j2 = 0; j2 < 16; ++j2) {
                        of[qt][0][j2] *= al;
                        of[qt][1][j2] *= al;
                    }
                }
                m_r += 10.0f;
                #pragma unroll
                for (int j2 = 0; j2 < 16; ++j2) nbv[j2] = -m_r;
            }
        }
    }

    // ---- finalize: per-split normalized O (fp16) + (m, l) ----
    _Float16* Opx = sp ? Op1 : Op0;
    #pragma unroll
    for (int qt = 0; qt < 2; ++qt) {
        const float l = l_r[qt] + __shfl_xor(l_r[qt], 32);
        const float inv = 1.0f / l;
        const int q = q0 + wave * 64 + qt * 32 + l31;
        const size_t R = rowBase + q;
        #pragma unroll
        for (int dt = 0; dt < 2; ++dt) {
            #pragma unroll
            for (int m4 = 0; m4 < 4; ++m4) {
                const int d0 = dt * 32 + 8 * m4 + 4 * g;
                Pkz z2;
                z2.h2[0] = __builtin_amdgcn_cvt_pkrtz(of[qt][dt][4 * m4 + 0] * inv,
                                                      of[qt][dt][4 * m4 + 1] * inv);
                z2.h2[1] = __builtin_amdgcn_cvt_pkrtz(of[qt][dt][4 * m4 + 2] * inv,
                                                      of[qt][dt][4 * m4 + 3] * inv);
                *(uint2*)(Opx + R * 512 + h * 64 + d0) = z2.u;
            }
        }
        if (lane < 32)
            Ml[((size_t)sp * BATCH * SEQ + R) * NHEADS + h] = make_float2(m_r, l);
    }
}

// ============================================================================
// attn_merge: flash-combine of the two K-split partials -> Oh.
// ============================================================================
__global__ __launch_bounds__(256)
void attn_merge(const _Float16* __restrict__ Op0, const _Float16* __restrict__ Op1,
                const float2* __restrict__ Ml, _Float16* __restrict__ Oh) {
    const int i4 = (blockIdx.x * 256 + threadIdx.x) * 4;
    const int R = i4 >> 9;
    const int c = i4 & 511;
    const int h = c >> 6;

    const float2 ml1 = Ml[(size_t)R * NHEADS + h];
    const float2 ml2 = Ml[(size_t)(BATCH * SEQ) * NHEADS + (size_t)R * NHEADS + h];
    const float m = fmaxf(ml1.x, ml2.x);
    float w1 = EXP2F(ml1.x - m) * ml1.y;
    float w2 = EXP2F(ml2.x - m) * ml2.y;
    const float inv = 1.0f / (w1 + w2);
    w1 *= inv; w2 *= inv;

    Un4 a, bb;
    a.u  = *(const uint2*)(Op0 + (size_t)R * 512 + c);
    bb.u = *(const uint2*)(Op1 + (size_t)R * 512 + c);

    Pkz hh;
    hh.h2[0] = __builtin_amdgcn_cvt_pkrtz(w1 * (float)a.h[0] + w2 * (float)bb.h[0],
                                          w1 * (float)a.h[1] + w2 * (float)bb.h[1]);
    hh.h2[1] = __builtin_amdgcn_cvt_pkrtz(w1 * (float)a.h[2] + w2 * (float)bb.h[2],
                                          w1 * (float)a.h[3] + w2 * (float)bb.h[3]);
    *(uint2*)(Oh + (size_t)R * 512 + c) = hh.u;
}

// ============================================================================
// Output projection: hi-only A and W. Double-buffered DMA. 128x64 block.
// ============================================================================
__global__ __launch_bounds__(256)
void gemm_out(const _Float16* __restrict__ Ah, const _Float16* __restrict__ Wh,
              const float* __restrict__ bias, float* __restrict__ C) {
    __shared__ __align__(16) _Float16 sAh[2][128 * 64];
    __shared__ __align__(16) _Float16 sWh[2][64 * 64];

    const int t    = threadIdx.x;
    const int lane = t & 63, wave = t >> 6;
    const int col  = lane & 15, quad = lane >> 4;
    const int wm   = (wave & 1) * 64, wn = (wave >> 1) * 32;
    const int m0   = blockIdx.y * 128, n0 = blockIdx.x * 64;

    const int subrow = lane >> 3;
    const int schunk = ((lane & 7) ^ subrow) * 8;

    #define STAGE_OUT(K0, BUF)                                                       \
        do {                                                                          \
            _Pragma("unroll")                                                         \
            for (int j = 0; j < 4; ++j) {                                             \
                const int rw = wave * 32 + j * 8;                                     \
                gload_lds16(Ah + (size_t)(m0 + rw + subrow) * 512 + (K0) + schunk,    \
                            &sAh[BUF][rw * 64]);                                      \
            }                                                                         \
            _Pragma("unroll")                                                         \
            for (int j = 0; j < 2; ++j) {                                             \
                const int rw = wave * 16 + j * 8;                                     \
                gload_lds16(Wh + (size_t)(n0 + rw + subrow) * 512 + (K0) + schunk,    \
                            &sWh[BUF][rw * 64]);                                      \
            }                                                                         \
        } while (0)

    f32x4 acc[4][2] = {};

    STAGE_OUT(0, 0);
    for (int ck = 0; ck < 8; ++ck) {
        const int cur = ck & 1;
        __syncthreads();
        if (ck + 1 < 8) STAGE_OUT((ck + 1) * 64, cur ^ 1);

        #pragma unroll
        for (int kc = 0; kc < 2; ++kc) {
            const int pos = ((kc * 4 + quad) ^ (col & 7)) * 8;
            half8 ahf[4], whf[2];
            #pragma unroll
            for (int mt = 0; mt < 4; ++mt)
                ahf[mt] = *(const half8*)&sAh[cur][(wm + mt * 16 + col) * 64 + pos];
            #pragma unroll
            for (int nt = 0; nt < 2; ++nt)
                whf[nt] = *(const half8*)&sWh[cur][(wn + nt * 16 + col) * 64 + pos];
            #pragma unroll
            for (int mt = 0; mt < 4; ++mt)
                #pragma unroll
                for (int nt = 0; nt < 2; ++nt)
                    acc[mt][nt] = MFMA16(ahf[mt], whf[nt], acc[mt][nt]);
        }
    }

    float bv2[2];
    #pragma unroll
    for (int nt = 0; nt < 2; ++nt) bv2[nt] = bias[n0 + wn + nt * 16 + col];

    #pragma unroll
    for (int mt = 0; mt < 4; ++mt) {
        const int m = m0 + wm + mt * 16 + quad * 4;
        #pragma unroll
        for (int nt = 0; nt < 2; ++nt) {
            const int n = n0 + wn + nt * 16 + col;
            #pragma unroll
            for (int r = 0; r < 4; ++r)
                C[(size_t)(m + r) * 512 + n] = acc[mt][nt][r] + bv2[nt];
        }
    }
}

// ============================================================================
extern "C" void kernel_launch(void* const* d_in, const int* in_sizes, int n_in,
                              void* d_out, int out_size, void* d_ws, size_t ws_size,
                              hipStream_t stream) {
    const float* query = (const float*)d_in[0];
    const float* key   = (const float*)d_in[1];
    const float* value = (const float*)d_in[2];
    const float* w_q   = (const float*)d_in[3];
    const float* b_q   = (const float*)d_in[4];
    const float* w_k   = (const float*)d_in[5];
    const float* b_k   = (const float*)d_in[6];
    const float* w_v   = (const float*)d_in[7];
    const float* b_v   = (const float*)d_in[8];
    const float* w_o   = (const float*)d_in[9];
    const float* b_o   = (const float*)d_in[10];
    float* out = (float*)d_out;

    const int WN = D_MODEL * D_MODEL;                     // 262144
    const size_t plane = (size_t)BATCH * SEQ * D_MODEL;   // 4.19M halves

    _Float16* base = (_Float16*)d_ws;
    _Float16* Aq16 = base;                 // scratch: Oh
    _Float16* Ak16 = Aq16 + plane;         // scratch
    _Float16* Av16 = Ak16 + plane;         // scratch: Op0
    _Float16* whq  = Av16 + plane;
    _Float16* whk  = whq + WN;
    _Float16* whv  = whk + WN;
    _Float16* who  = whv + WN;
    _Float16* Qf   = who + WN;
    _Float16* Kf   = Qf + plane;
    _Float16* Vtf  = Kf + plane;
    _Float16* Op1  = Vtf + plane;
    float2*   Ml   = (float2*)(Op1 + plane);  // 2*BATCH*SEQ*NHEADS float2 = 1 MB
    _Float16* Oh   = Aq16;
    _Float16* Op0  = Av16;

    dim3 blk(256);

    hipLaunchKernelGGL(prep, dim3(4 * WBLK), blk, 0, stream,
                       w_q, w_k, w_v, w_o, whq, whk, whv, who);

    hipLaunchKernelGGL(gemm_qkv, dim3(D_MODEL / 128, BATCH * SEQ / 128, 3), blk, 0, stream,
                       query, key, value,
                       whq, whk, whv,
                       b_q, b_k, b_v, Qf, Kf, Vtf);

    hipLaunchKernelGGL(attn_mfma, dim3(NHEADS * BATCH * NSPLIT, SEQ / 256), blk, 0, stream,
                       Qf, Kf, Vtf, Op0, Op1, Ml);

    hipLaunchKernelGGL(attn_merge, dim3(BATCH * SEQ * D_MODEL / 4 / 256), blk, 0, stream,
                       Op0, Op1, Ml, Oh);

    hipLaunchKernelGGL(gemm_out, dim3(D_MODEL / 64, BATCH * SEQ / 128), blk, 0, stream,
                       Oh, who, b_o, out);
}

// Round 9
// 235.839 us; speedup vs baseline: 3.7336x; 1.0181x over previous
//
#include <hip/hip_runtime.h>
#include <math.h>

#define D_MODEL 512
#define NHEADS 8
#define DK 64
#define BATCH 2
#define SEQ 4096
#define NIT 32          // 2048 keys per split / 64-key tiles
// log2(e)/8 folded into Q projection: scores in log2 domain, softmax uses exp2.
#define ATTN_SCALE 0.18033688011112043f

typedef _Float16 half8 __attribute__((ext_vector_type(8)));
typedef _Float16 half4 __attribute__((ext_vector_type(4)));
typedef __fp16 pkhalf2 __attribute__((ext_vector_type(2)));
typedef float f32x4 __attribute__((ext_vector_type(4)));
typedef float f32x16 __attribute__((ext_vector_type(16)));

union Pk8 { _Float16 h[8]; uint4 u; };
union Pk4 { _Float16 h[4]; uint2 u; };
union Pkz { pkhalf2 h2[2]; uint2 u; };
union Un4 { uint2 u; _Float16 h[4]; };
union PFu { unsigned int u[4]; half8 h8; };

#if __has_builtin(__builtin_amdgcn_exp2f)
#define EXP2F __builtin_amdgcn_exp2f
#else
#define EXP2F exp2f
#endif

#define MFMA16(a, b, c) __builtin_amdgcn_mfma_f32_16x16x32_f16((a), (b), (c), 0, 0, 0)
#define MFMA32(a, b, c) __builtin_amdgcn_mfma_f32_32x32x16_f16((a), (b), (c), 0, 0, 0)

// in-place cross-half lane exchange: x[32..63] <- y_old[0..31], y[0..31] <- x_old[32..63]
#define PLSWAP(x, y) asm volatile("v_permlane32_swap_b32 %0, %1" : "+v"(x), "+v"(y))

__device__ __forceinline__ unsigned int cvtpk(float a, float b) {
    union { pkhalf2 h; unsigned int u; } u_;
    u_.h = __builtin_amdgcn_cvt_pkrtz(a, b);
    return u_.u;
}

__device__ __forceinline__ void gload_lds16(const _Float16* g, _Float16* l) {
    __builtin_amdgcn_global_load_lds(
        (const __attribute__((address_space(1))) void*)g,
        (__attribute__((address_space(3))) void*)l, 16, 0, 0);
}

// ============================================================================
// prep: fp32->fp16 for the 4 weight hi-planes ONLY.
// ============================================================================
#define WBLK 256
__global__ __launch_bounds__(256)
void prep(const float* __restrict__ wq, const float* __restrict__ wk,
          const float* __restrict__ wv, const float* __restrict__ wo,
          _Float16* __restrict__ hq, _Float16* __restrict__ hk,
          _Float16* __restrict__ hv, _Float16* __restrict__ ho) {
    int gid = blockIdx.x;
    const int w = gid / WBLK;
    gid -= w * WBLK;
    const float* src = w == 0 ? wq : (w == 1 ? wk : (w == 2 ? wv : wo));
    _Float16* hi     = w == 0 ? hq : (w == 1 ? hk : (w == 2 ? hv : ho));
    const int i = (gid * 256 + threadIdx.x) * 4;
    float4 v = *(const float4*)(src + i);
    Pkz h;
    h.h2[0] = __builtin_amdgcn_cvt_pkrtz(v.x, v.y);
    h.h2[1] = __builtin_amdgcn_cvt_pkrtz(v.z, v.w);
    *(uint2*)(hi + i) = h.u;
}

// ============================================================================
// QKV projection GEMM (r8 form): A read directly as fp32, converted during
// reg-staging; W fp16 via DMA. 128x128, BK=64, double-buffered.
// ============================================================================
__global__ __launch_bounds__(256)
void gemm_qkv(const float* __restrict__ Aq, const float* __restrict__ Ak,
              const float* __restrict__ Av,
              const _Float16* __restrict__ Whq, const _Float16* __restrict__ Whk,
              const _Float16* __restrict__ Whv,
              const float* __restrict__ bq, const float* __restrict__ bk,
              const float* __restrict__ bv,
              _Float16* __restrict__ Qf, _Float16* __restrict__ Kf,
              _Float16* __restrict__ Vtf) {
    const int z = blockIdx.z;
    const float*    A    = z == 0 ? Aq  : (z == 1 ? Ak  : Av);
    const _Float16* Wh   = z == 0 ? Whq : (z == 1 ? Whk : Whv);
    const float*    bias = z == 0 ? bq  : (z == 1 ? bk  : bv);

    __shared__ __align__(16) _Float16 sA[2][128 * 64];
    __shared__ __align__(16) _Float16 sW[2][128 * 64];

    const int t    = threadIdx.x;
    const int lane = t & 63, wave = t >> 6;
    const int col  = lane & 15, quad = lane >> 4;
    const int wm   = (wave & 1) * 64, wn = (wave >> 1) * 64;
    const int m0   = blockIdx.y * 128, n0 = blockIdx.x * 128;

    const int subrow = lane >> 3;
    const int schunk = ((lane & 7) ^ subrow) * 8;

    const float* aBase = A + (size_t)(m0 + wave * 32 + subrow) * 512 + schunk;

    float4 ar[4][2];
    #define LOAD_A(K0)                                                            \
        do {                                                                       \
            _Pragma("unroll")                                                      \
            for (int j = 0; j < 4; ++j) {                                          \
                const float* s = aBase + (size_t)(j * 8) * 512 + (K0);             \
                ar[j][0] = *(const float4*)s;                                      \
                ar[j][1] = *(const float4*)(s + 4);                                \
            }                                                                      \
        } while (0)
    #define WRITE_A(BUF)                                                           \
        do {                                                                       \
            _Pragma("unroll")                                                      \
            for (int j = 0; j < 4; ++j) {                                          \
                uint4 p;                                                           \
                p.x = cvtpk(ar[j][0].x, ar[j][0].y);                               \
                p.y = cvtpk(ar[j][0].z, ar[j][0].w);                               \
                p.z = cvtpk(ar[j][1].x, ar[j][1].y);                               \
                p.w = cvtpk(ar[j][1].z, ar[j][1].w);                               \
                *(uint4*)&sA[BUF][(wave * 32 + j * 8) * 64 + lane * 8] = p;        \
            }                                                                      \
        } while (0)
    #define STAGE_W(K0, BUF)                                                       \
        do {                                                                       \
            _Pragma("unroll")                                                      \
            for (int j = 0; j < 4; ++j) {                                          \
                const int rw = wave * 32 + j * 8;                                  \
                gload_lds16(Wh + (size_t)(n0 + rw + subrow) * 512 + (K0) + schunk, \
                            &sW[BUF][rw * 64]);                                    \
            }                                                                      \
        } while (0)

    f32x4 acc[4][4] = {};

    STAGE_W(0, 0);
    LOAD_A(0);
    WRITE_A(0);

    for (int ck = 0; ck < 8; ++ck) {
        const int cur = ck & 1;
        __syncthreads();
        if (ck + 1 < 8) {
            STAGE_W((ck + 1) * 64, cur ^ 1);
            LOAD_A((ck + 1) * 64);
        }

        #pragma unroll
        for (int kc = 0; kc < 2; ++kc) {
            const int pos = ((kc * 4 + quad) ^ (col & 7)) * 8;
            half8 af[4], wf[4];
            #pragma unroll
            for (int mt = 0; mt < 4; ++mt)
                af[mt] = *(const half8*)&sA[cur][(wm + mt * 16 + col) * 64 + pos];
            #pragma unroll
            for (int nt = 0; nt < 4; ++nt)
                wf[nt] = *(const half8*)&sW[cur][(wn + nt * 16 + col) * 64 + pos];
            #pragma unroll
            for (int mt = 0; mt < 4; ++mt)
                #pragma unroll
                for (int nt = 0; nt < 4; ++nt)
                    acc[mt][nt] = MFMA16(af[mt], wf[nt], acc[mt][nt]);
        }

        if (ck + 1 < 8) WRITE_A(cur ^ 1);
    }

    float bv4[4];
    #pragma unroll
    for (int nt = 0; nt < 4; ++nt) bv4[nt] = bias[n0 + wn + nt * 16 + col];

    if (z < 2) {
        _Float16* Out = z == 0 ? Qf : Kf;
        const float alpha = z == 0 ? ATTN_SCALE : 1.0f;
        #pragma unroll
        for (int mt = 0; mt < 4; ++mt) {
            const int m = m0 + wm + mt * 16 + quad * 4;
            #pragma unroll
            for (int nt = 0; nt < 4; ++nt) {
                const int n = n0 + wn + nt * 16 + col;
                #pragma unroll
                for (int r = 0; r < 4; ++r)
                    Out[(size_t)(m + r) * 512 + n] = (_Float16)((acc[mt][nt][r] + bv4[nt]) * alpha);
            }
        }
    } else {
        #pragma unroll
        for (int mt = 0; mt < 4; ++mt) {
            const int m = m0 + wm + mt * 16 + quad * 4;
            const int b = m >> 12, s = m & (SEQ - 1);
            #pragma unroll
            for (int nt = 0; nt < 4; ++nt) {
                const int n = n0 + wn + nt * 16 + col;
                const int hh = n >> 6, d = n & (DK - 1);
                Pk4 p;
                #pragma unroll
                for (int r = 0; r < 4; ++r)
                    p.h[r] = (_Float16)(acc[mt][nt][r] + bv4[nt]);
                *(uint2*)&Vtf[((size_t)((b * NHEADS + hh) * DK + d)) * SEQ + s] = p.u;
            }
        }
    }
}

// ============================================================================
// Flash attention, r9: BOTH K-splits in one 512-thread block + in-block merge.
//  - waves 0-3 = split 0 (keys 0..2047), waves 4-7 = split 1 (keys 2048..4095),
//    same 256 q rows. Each split-half has its own 32 KB K/V double-buffer
//    (64 KB total). Main loop is r8's, per split-half.
//  - Final flash-combine happens IN BLOCK: split 0 parks normalized O (fp16,
//    XOR-swizzled, aliasing the dead sK region) + (m,l) in LDS; split 1
//    combines and writes final Oh. attn_merge kernel and the Op0/Op1/Ml
//    planes are deleted: -33 MB HBM traffic, -1 kernel launch.
//  - Grid (16,16)=256 blocks x 512 thr = same 8 waves/CU as r8.
// ============================================================================
__global__ __launch_bounds__(512)
void attn_mfma(const _Float16* __restrict__ Qf, const _Float16* __restrict__ Kf,
               const _Float16* __restrict__ Vtf, _Float16* __restrict__ Oh) {
    __shared__ __align__(16) _Float16 sKall[2 * 2 * 64 * 64];  // [sp][cur] 32 KB
    __shared__ __align__(16) _Float16 sVall[2 * 2 * 64 * 64];  // [sp][cur] 32 KB
    __shared__ float2 sMl[256];                                // split-0 (m,l)

    const int t    = threadIdx.x;
    const int lane = t & 63;
    const int wave = t >> 6;          // 0..7
    const int sp   = wave >> 2;       // split
    const int w4   = wave & 3;        // wave within split
    const int l31  = lane & 31;
    const int g    = lane >> 5;

    // grid: x = h + 8*b (XCD = h), y = qblock
    const int h  = blockIdx.x & (NHEADS - 1);
    const int b  = blockIdx.x >> 3;
    const int q0 = blockIdx.y * 256;
    const int kBase = sp * (SEQ / 2);

    const size_t rowBase = (size_t)b * SEQ;
    const size_t vBase   = ((size_t)(b * NHEADS + h)) * DK * SEQ;

    _Float16* sK0 = sKall + sp * 2 * 4096;
    _Float16* sV0 = sVall + sp * 2 * 4096;

    // ---- DMA pointers; issue K/V tile 0 immediately ----
    const int subrow = lane >> 3;
    const int schunk = ((lane & 7) ^ subrow) * 8;
    const _Float16* kP[2];
    const _Float16* vP[2];
    #pragma unroll
    for (int j = 0; j < 2; ++j) {
        const int rw = w4 * 16 + j * 8;
        kP[j] = Kf + (rowBase + kBase + rw + subrow) * 512 + h * 64 + schunk;
        vP[j] = Vtf + vBase + (size_t)(rw + subrow) * SEQ + kBase + schunk;
        gload_lds16(kP[j], sK0 + rw * 64);
        gload_lds16(vP[j], sV0 + rw * 64);
        kP[j] += 64 * 512;
        vP[j] += 64;
    }

    // ---- Q fragments direct from global: qf[qt][kc] ----
    half8 qf[2][4];
    #pragma unroll
    for (int qt = 0; qt < 2; ++qt)
        #pragma unroll
        for (int kc = 0; kc < 4; ++kc)
            qf[qt][kc] = *(const half8*)(Qf +
                (rowBase + q0 + w4 * 64 + qt * 32 + l31) * 512 +
                h * 64 + kc * 16 + g * 8);

    const int rs = l31 & 7;   // row-XOR swizzle key for K/V LDS reads

    float m_r = 0.0f;
    f32x16 nbv = {};          // -m_r broadcast; all-zero in the common path
    float l_r[2] = { 0.0f, 0.0f };
    f32x16 of[2][2] = {};     // [qt][dt]

    for (int itp = 0; itp < NIT; itp += 2) {
        #pragma unroll
        for (int cur = 0; cur < 2; ++cur) {     // compile-time cur
            const int it = itp + cur;
            _Float16* sK = sK0 + cur * 4096;
            _Float16* sV = sV0 + cur * 4096;
            __syncthreads();   // drains DMA(it) + frees buf cur^1
            if (it + 1 < NIT) {
                #pragma unroll
                for (int j = 0; j < 2; ++j) {
                    const int rw = w4 * 16 + j * 8;
                    gload_lds16(kP[j], sK0 + (cur ^ 1) * 4096 + rw * 64);
                    gload_lds16(vP[j], sV0 + (cur ^ 1) * 4096 + rw * 64);
                    kP[j] += 64 * 512;
                    vP[j] += 64;
                }
            }

            #pragma unroll
            for (int kt = 0; kt < 2; ++kt) {
                // ---- S^T = K · Q^T : 8 MFMA, K frag shared across qt ----
                f32x16 sf0, sf1;
                __builtin_amdgcn_s_setprio(1);
                #pragma unroll
                for (int kc = 0; kc < 4; ++kc) {
                    const int pos = ((kc * 2 + g) ^ rs) * 8;
                    half8 kf = *(const half8*)&sK[(kt * 32 + l31) * 64 + pos];
                    sf0 = MFMA32(kf, qf[0][kc], kc == 0 ? nbv : sf0);
                    sf1 = MFMA32(kf, qf[1][kc], kc == 0 ? nbv : sf1);
                }
                __builtin_amdgcn_s_setprio(0);

                // ---- softmax in-register; l accumulated on VALU ----
                float lrs0 = 0.0f, lrs1 = 0.0f;
                #pragma unroll
                for (int j2 = 0; j2 < 16; ++j2) {
                    sf0[j2] = EXP2F(sf0[j2]);  lrs0 += sf0[j2];
                    sf1[j2] = EXP2F(sf1[j2]);  lrs1 += sf1[j2];
                }
                l_r[0] += lrs0;
                l_r[1] += lrs1;

                // ---- P^T -> B frags: 8 cvt_pk + 4 permlane per qt ----
                PFu pf0[2], pf1[2];
                #define MKPF(P, PF)                                                  \
                    do {                                                             \
                        unsigned int x1 = cvtpk(P[0], P[1]),  x2 = cvtpk(P[2], P[3]);\
                        unsigned int y1 = cvtpk(P[4], P[5]),  y2 = cvtpk(P[6], P[7]);\
                        PLSWAP(x1, y1); PLSWAP(x2, y2);                              \
                        PF[0].u[0] = x1; PF[0].u[1] = x2;                            \
                        PF[0].u[2] = y1; PF[0].u[3] = y2;                            \
                        unsigned int a1 = cvtpk(P[8], P[9]),  a2 = cvtpk(P[10], P[11]);\
                        unsigned int b1 = cvtpk(P[12], P[13]), b2 = cvtpk(P[14], P[15]);\
                        PLSWAP(a1, b1); PLSWAP(a2, b2);                              \
                        PF[1].u[0] = a1; PF[1].u[1] = a2;                            \
                        PF[1].u[2] = b1; PF[1].u[3] = b2;                            \
                    } while (0)
                MKPF(sf0, pf0);
                MKPF(sf1, pf1);
                #undef MKPF

                // ---- O^T += V^T·P^T (V frag shared across qt) ----
                __builtin_amdgcn_s_setprio(1);
                #pragma unroll
                for (int ks2 = 0; ks2 < 2; ++ks2) {
                    const int ks = kt * 2 + ks2;
                    const int pos = ((ks * 2 + g) ^ rs) * 8;
                    half8 v0 = *(const half8*)&sV[l31 * 64 + pos];
                    half8 v1 = *(const half8*)&sV[(32 + l31) * 64 + pos];
                    of[0][0] = MFMA32(v0, pf0[ks2].h8, of[0][0]);
                    of[0][1] = MFMA32(v1, pf0[ks2].h8, of[0][1]);
                    of[1][0] = MFMA32(v0, pf1[ks2].h8, of[1][0]);
                    of[1][1] = MFMA32(v1, pf1[ks2].h8, of[1][1]);
                }
                __builtin_amdgcn_s_setprio(0);
            }

            // ---- rare re-center: running l too large -> scale down 2^-10 ----
            if (__any(fmaxf(l_r[0], l_r[1]) > 1048576.0f)) {
                const float al = 0.0009765625f;   // 2^-10
                #pragma unroll
                for (int qt = 0; qt < 2; ++qt) {
                    l_r[qt] *= al;
                    #pragma unroll
                    for (int j2 = 0; j2 < 16; ++j2) {
                        of[qt][0][j2] *= al;
                        of[qt][1][j2] *= al;
                    }
                }
                m_r += 10.0f;
                #pragma unroll
                for (int j2 = 0; j2 < 16; ++j2) nbv[j2] = -m_r;
            }
        }
    }

    // ======== in-block flash combine (split 0 -> LDS, split 1 merges) ========
    __syncthreads();   // all LDS reads of sK/sV done; sKall region reusable
    _Float16* sOex = sKall;   // 256 q x 64 d fp16, XOR-swizzled (32 KB exact)

    if (sp == 0) {
        #pragma unroll
        for (int qt = 0; qt < 2; ++qt) {
            const float l = l_r[qt] + __shfl_xor(l_r[qt], 32);
            const float inv = 1.0f / l;
            const int ql = w4 * 64 + qt * 32 + l31;
            #pragma unroll
            for (int dt = 0; dt < 2; ++dt) {
                #pragma unroll
                for (int m4 = 0; m4 < 4; ++m4) {
                    const int d0 = dt * 32 + 8 * m4 + 4 * g;
                    const int s = (d0 >> 2) ^ ((ql & 7) << 1);
                    Pkz z2;
                    z2.h2[0] = __builtin_amdgcn_cvt_pkrtz(of[qt][dt][4 * m4 + 0] * inv,
                                                          of[qt][dt][4 * m4 + 1] * inv);
                    z2.h2[1] = __builtin_amdgcn_cvt_pkrtz(of[qt][dt][4 * m4 + 2] * inv,
                                                          of[qt][dt][4 * m4 + 3] * inv);
                    *(uint2*)&sOex[ql * 64 + s * 4] = z2.u;
                }
            }
            if (lane < 32) sMl[ql] = make_float2(m_r, l);
        }
    }
    __syncthreads();
    if (sp == 1) {
        #pragma unroll
        for (int qt = 0; qt < 2; ++qt) {
            const float lB = l_r[qt] + __shfl_xor(l_r[qt], 32);
            const int ql = w4 * 64 + qt * 32 + l31;
            const float2 mlA = sMl[ql];
            const float m = fmaxf(mlA.x, m_r);
            float wA = EXP2F(mlA.x - m) * mlA.y;
            float wB = EXP2F(m_r - m) * lB;
            const float inv = 1.0f / (wA + wB);
            wA *= inv;
            const float wBn = wB * inv / lB;   // applied to unnormalized of
            const size_t R = rowBase + q0 + ql;
            #pragma unroll
            for (int dt = 0; dt < 2; ++dt) {
                #pragma unroll
                for (int m4 = 0; m4 < 4; ++m4) {
                    const int d0 = dt * 32 + 8 * m4 + 4 * g;
                    const int s = (d0 >> 2) ^ ((ql & 7) << 1);
                    Un4 oa;
                    oa.u = *(const uint2*)&sOex[ql * 64 + s * 4];
                    Pkz z2;
                    z2.h2[0] = __builtin_amdgcn_cvt_pkrtz(
                        wA * (float)oa.h[0] + wBn * of[qt][dt][4 * m4 + 0],
                        wA * (float)oa.h[1] + wBn * of[qt][dt][4 * m4 + 1]);
                    z2.h2[1] = __builtin_amdgcn_cvt_pkrtz(
                        wA * (float)oa.h[2] + wBn * of[qt][dt][4 * m4 + 2],
                        wA * (float)oa.h[3] + wBn * of[qt][dt][4 * m4 + 3]);
                    *(uint2*)(Oh + R * 512 + h * 64 + d0) = z2.u;
                }
            }
        }
    }
}

// ============================================================================
// Output projection: hi-only A and W. Double-buffered DMA. 128x64 block.
// ============================================================================
__global__ __launch_bounds__(256)
void gemm_out(const _Float16* __restrict__ Ah, const _Float16* __restrict__ Wh,
              const float* __restrict__ bias, float* __restrict__ C) {
    __shared__ __align__(16) _Float16 sAh[2][128 * 64];
    __shared__ __align__(16) _Float16 sWh[2][64 * 64];

    const int t    = threadIdx.x;
    const int lane = t & 63, wave = t >> 6;
    const int col  = lane & 15, quad = lane >> 4;
    const int wm   = (wave & 1) * 64, wn = (wave >> 1) * 32;
    const int m0   = blockIdx.y * 128, n0 = blockIdx.x * 64;

    const int subrow = lane >> 3;
    const int schunk = ((lane & 7) ^ subrow) * 8;

    #define STAGE_OUT(K0, BUF)                                                       \
        do {                                                                          \
            _Pragma("unroll")                                                         \
            for (int j = 0; j < 4; ++j) {                                             \
                const int rw = wave * 32 + j * 8;                                     \
                gload_lds16(Ah + (size_t)(m0 + rw + subrow) * 512 + (K0) + schunk,    \
                            &sAh[BUF][rw * 64]);                                      \
            }                                                                         \
            _Pragma("unroll")                                                         \
            for (int j = 0; j < 2; ++j) {                                             \
                const int rw = wave * 16 + j * 8;                                     \
                gload_lds16(Wh + (size_t)(n0 + rw + subrow) * 512 + (K0) + schunk,    \
                            &sWh[BUF][rw * 64]);                                      \
            }                                                                         \
        } while (0)

    f32x4 acc[4][2] = {};

    STAGE_OUT(0, 0);
    for (int ck = 0; ck < 8; ++ck) {
        const int cur = ck & 1;
        __syncthreads();
        if (ck + 1 < 8) STAGE_OUT((ck + 1) * 64, cur ^ 1);

        #pragma unroll
        for (int kc = 0; kc < 2; ++kc) {
            const int pos = ((kc * 4 + quad) ^ (col & 7)) * 8;
            half8 ahf[4], whf[2];
            #pragma unroll
            for (int mt = 0; mt < 4; ++mt)
                ahf[mt] = *(const half8*)&sAh[cur][(wm + mt * 16 + col) * 64 + pos];
            #pragma unroll
            for (int nt = 0; nt < 2; ++nt)
                whf[nt] = *(const half8*)&sWh[cur][(wn + nt * 16 + col) * 64 + pos];
            #pragma unroll
            for (int mt = 0; mt < 4; ++mt)
                #pragma unroll
                for (int nt = 0; nt < 2; ++nt)
                    acc[mt][nt] = MFMA16(ahf[mt], whf[nt], acc[mt][nt]);
        }
    }

    float bv2[2];
    #pragma unroll
    for (int nt = 0; nt < 2; ++nt) bv2[nt] = bias[n0 + wn + nt * 16 + col];

    #pragma unroll
    for (int mt = 0; mt < 4; ++mt) {
        const int m = m0 + wm + mt * 16 + quad * 4;
        #pragma unroll
        for (int nt = 0; nt < 2; ++nt) {
            const int n = n0 + wn + nt * 16 + col;
            #pragma unroll
            for (int r = 0; r < 4; ++r)
                C[(size_t)(m + r) * 512 + n] = acc[mt][nt][r] + bv2[nt];
        }
    }
}

// ============================================================================
extern "C" void kernel_launch(void* const* d_in, const int* in_sizes, int n_in,
                              void* d_out, int out_size, void* d_ws, size_t ws_size,
                              hipStream_t stream) {
    const float* query = (const float*)d_in[0];
    const float* key   = (const float*)d_in[1];
    const float* value = (const float*)d_in[2];
    const float* w_q   = (const float*)d_in[3];
    const float* b_q   = (const float*)d_in[4];
    const float* w_k   = (const float*)d_in[5];
    const float* b_k   = (const float*)d_in[6];
    const float* w_v   = (const float*)d_in[7];
    const float* b_v   = (const float*)d_in[8];
    const float* w_o   = (const float*)d_in[9];
    const float* b_o   = (const float*)d_in[10];
    float* out = (float*)d_out;

    const int WN = D_MODEL * D_MODEL;                     // 262144
    const size_t plane = (size_t)BATCH * SEQ * D_MODEL;   // 4.19M halves

    _Float16* base = (_Float16*)d_ws;
    _Float16* Oh   = base;                 // attn output (fp16)
    _Float16* whq  = Oh + plane;
    _Float16* whk  = whq + WN;
    _Float16* whv  = whk + WN;
    _Float16* who  = whv + WN;
    _Float16* Qf   = who + WN;
    _Float16* Kf   = Qf + plane;
    _Float16* Vtf  = Kf + plane;

    dim3 blk(256);

    hipLaunchKernelGGL(prep, dim3(4 * WBLK), blk, 0, stream,
                       w_q, w_k, w_v, w_o, whq, whk, whv, who);

    hipLaunchKernelGGL(gemm_qkv, dim3(D_MODEL / 128, BATCH * SEQ / 128, 3), blk, 0, stream,
                       query, key, value,
                       whq, whk, whv,
                       b_q, b_k, b_v, Qf, Kf, Vtf);

    hipLaunchKernelGGL(attn_mfma, dim3(NHEADS * BATCH, SEQ / 256), dim3(512), 0, stream,
                       Qf, Kf, Vtf, Oh);

    hipLaunchKernelGGL(gemm_out, dim3(D_MODEL / 64, BATCH * SEQ / 128), blk, 0, stream,
                       Oh, who, b_o, out);
}

// Round 10
// 228.816 us; speedup vs baseline: 3.8482x; 1.0307x over previous
//
#include <hip/hip_runtime.h>
#include <math.h>

#define D_MODEL 512
#define NHEADS 8
#define DK 64
#define BATCH 2
#define SEQ 4096
#define NIT 32          // 2048 keys per split / 64-key tiles
// log2(e)/8 folded into Q projection: scores in log2 domain, softmax uses exp2.
#define ATTN_SCALE 0.18033688011112043f

typedef _Float16 half8 __attribute__((ext_vector_type(8)));
typedef _Float16 half4 __attribute__((ext_vector_type(4)));
typedef __fp16 pkhalf2 __attribute__((ext_vector_type(2)));
typedef float f32x4 __attribute__((ext_vector_type(4)));
typedef float f32x16 __attribute__((ext_vector_type(16)));

union Pk8 { _Float16 h[8]; uint4 u; };
union Pk4 { _Float16 h[4]; uint2 u; };
union Pkz { pkhalf2 h2[2]; uint2 u; };
union Un4 { uint2 u; _Float16 h[4]; };
union PFu { unsigned int u[4]; half8 h8; };

#if __has_builtin(__builtin_amdgcn_exp2f)
#define EXP2F __builtin_amdgcn_exp2f
#else
#define EXP2F exp2f
#endif

#define MFMA16(a, b, c) __builtin_amdgcn_mfma_f32_16x16x32_f16((a), (b), (c), 0, 0, 0)
#define MFMA32(a, b, c) __builtin_amdgcn_mfma_f32_32x32x16_f16((a), (b), (c), 0, 0, 0)

// in-place cross-half lane exchange: x[32..63] <- y_old[0..31], y[0..31] <- x_old[32..63]
#define PLSWAP(x, y) asm volatile("v_permlane32_swap_b32 %0, %1" : "+v"(x), "+v"(y))

__device__ __forceinline__ unsigned int cvtpk(float a, float b) {
    union { pkhalf2 h; unsigned int u; } u_;
    u_.h = __builtin_amdgcn_cvt_pkrtz(a, b);
    return u_.u;
}

__device__ __forceinline__ void gload_lds16(const _Float16* g, _Float16* l) {
    __builtin_amdgcn_global_load_lds(
        (const __attribute__((address_space(1))) void*)g,
        (__attribute__((address_space(3))) void*)l, 16, 0, 0);
}

// ============================================================================
// QKV projection GEMM, r10: BOTH A and W read directly as fp32 and converted
// during reg-staging (float4 x2 -> cvt_pkrtz -> ds_write_b128). prep kernel is
// DELETED (kernel count 4 -> 3). W slices are L2-resident (3 MB total), so the
// doubled W bytes are L2 hits; A path identical to r8's proven form.
// ============================================================================
__global__ __launch_bounds__(256)
void gemm_qkv(const float* __restrict__ Aq, const float* __restrict__ Ak,
              const float* __restrict__ Av,
              const float* __restrict__ Wq, const float* __restrict__ Wk,
              const float* __restrict__ Wv,
              const float* __restrict__ bq, const float* __restrict__ bk,
              const float* __restrict__ bv,
              _Float16* __restrict__ Qf, _Float16* __restrict__ Kf,
              _Float16* __restrict__ Vtf) {
    const int z = blockIdx.z;
    const float* A    = z == 0 ? Aq : (z == 1 ? Ak : Av);
    const float* W    = z == 0 ? Wq : (z == 1 ? Wk : Wv);
    const float* bias = z == 0 ? bq : (z == 1 ? bk : bv);

    __shared__ __align__(16) _Float16 sA[2][128 * 64];
    __shared__ __align__(16) _Float16 sW[2][128 * 64];

    const int t    = threadIdx.x;
    const int lane = t & 63, wave = t >> 6;
    const int col  = lane & 15, quad = lane >> 4;
    const int wm   = (wave & 1) * 64, wn = (wave >> 1) * 64;
    const int m0   = blockIdx.y * 128, n0 = blockIdx.x * 128;

    const int subrow = lane >> 3;
    const int schunk = ((lane & 7) ^ subrow) * 8;

    const float* aBase = A + (size_t)(m0 + wave * 32 + subrow) * 512 + schunk;
    const float* wBase = W + (size_t)(n0 + wave * 32 + subrow) * 512 + schunk;

    float4 ar[4][2], wr[4][2];
    #define LOAD_AW(K0)                                                           \
        do {                                                                       \
            _Pragma("unroll")                                                      \
            for (int j = 0; j < 4; ++j) {                                          \
                const float* sa = aBase + (size_t)(j * 8) * 512 + (K0);            \
                const float* sw = wBase + (size_t)(j * 8) * 512 + (K0);            \
                ar[j][0] = *(const float4*)sa;                                     \
                ar[j][1] = *(const float4*)(sa + 4);                               \
                wr[j][0] = *(const float4*)sw;                                     \
                wr[j][1] = *(const float4*)(sw + 4);                               \
            }                                                                      \
        } while (0)
    #define WRITE_AW(BUF)                                                          \
        do {                                                                       \
            _Pragma("unroll")                                                      \
            for (int j = 0; j < 4; ++j) {                                          \
                uint4 p;                                                           \
                p.x = cvtpk(ar[j][0].x, ar[j][0].y);                               \
                p.y = cvtpk(ar[j][0].z, ar[j][0].w);                               \
                p.z = cvtpk(ar[j][1].x, ar[j][1].y);                               \
                p.w = cvtpk(ar[j][1].z, ar[j][1].w);                               \
                *(uint4*)&sA[BUF][(wave * 32 + j * 8) * 64 + lane * 8] = p;        \
                uint4 q;                                                           \
                q.x = cvtpk(wr[j][0].x, wr[j][0].y);                               \
                q.y = cvtpk(wr[j][0].z, wr[j][0].w);                               \
                q.z = cvtpk(wr[j][1].x, wr[j][1].y);                               \
                q.w = cvtpk(wr[j][1].z, wr[j][1].w);                               \
                *(uint4*)&sW[BUF][(wave * 32 + j * 8) * 64 + lane * 8] = q;        \
            }                                                                      \
        } while (0)

    f32x4 acc[4][4] = {};

    LOAD_AW(0);
    WRITE_AW(0);

    for (int ck = 0; ck < 8; ++ck) {
        const int cur = ck & 1;
        __syncthreads();
        if (ck + 1 < 8) LOAD_AW((ck + 1) * 64);

        #pragma unroll
        for (int kc = 0; kc < 2; ++kc) {
            const int pos = ((kc * 4 + quad) ^ (col & 7)) * 8;
            half8 af[4], wf[4];
            #pragma unroll
            for (int mt = 0; mt < 4; ++mt)
                af[mt] = *(const half8*)&sA[cur][(wm + mt * 16 + col) * 64 + pos];
            #pragma unroll
            for (int nt = 0; nt < 4; ++nt)
                wf[nt] = *(const half8*)&sW[cur][(wn + nt * 16 + col) * 64 + pos];
            #pragma unroll
            for (int mt = 0; mt < 4; ++mt)
                #pragma unroll
                for (int nt = 0; nt < 4; ++nt)
                    acc[mt][nt] = MFMA16(af[mt], wf[nt], acc[mt][nt]);
        }

        if (ck + 1 < 8) WRITE_AW(cur ^ 1);
    }

    float bv4[4];
    #pragma unroll
    for (int nt = 0; nt < 4; ++nt) bv4[nt] = bias[n0 + wn + nt * 16 + col];

    if (z < 2) {
        _Float16* Out = z == 0 ? Qf : Kf;
        const float alpha = z == 0 ? ATTN_SCALE : 1.0f;
        #pragma unroll
        for (int mt = 0; mt < 4; ++mt) {
            const int m = m0 + wm + mt * 16 + quad * 4;
            #pragma unroll
            for (int nt = 0; nt < 4; ++nt) {
                const int n = n0 + wn + nt * 16 + col;
                #pragma unroll
                for (int r = 0; r < 4; ++r)
                    Out[(size_t)(m + r) * 512 + n] = (_Float16)((acc[mt][nt][r] + bv4[nt]) * alpha);
            }
        }
    } else {
        #pragma unroll
        for (int mt = 0; mt < 4; ++mt) {
            const int m = m0 + wm + mt * 16 + quad * 4;
            const int b = m >> 12, s = m & (SEQ - 1);
            #pragma unroll
            for (int nt = 0; nt < 4; ++nt) {
                const int n = n0 + wn + nt * 16 + col;
                const int hh = n >> 6, d = n & (DK - 1);
                Pk4 p;
                #pragma unroll
                for (int r = 0; r < 4; ++r)
                    p.h[r] = (_Float16)(acc[mt][nt][r] + bv4[nt]);
                *(uint2*)&Vtf[((size_t)((b * NHEADS + hh) * DK + d)) * SEQ + s] = p.u;
            }
        }
    }
}

// ============================================================================
// Flash attention (r9 form, unchanged): both K-splits in one 512-thread block,
// in-block flash merge, 64 q/wave, register P via permlane, 32 MFMA32/wave-iter.
// ============================================================================
__global__ __launch_bounds__(512)
void attn_mfma(const _Float16* __restrict__ Qf, const _Float16* __restrict__ Kf,
               const _Float16* __restrict__ Vtf, _Float16* __restrict__ Oh) {
    __shared__ __align__(16) _Float16 sKall[2 * 2 * 64 * 64];  // [sp][cur] 32 KB
    __shared__ __align__(16) _Float16 sVall[2 * 2 * 64 * 64];  // [sp][cur] 32 KB
    __shared__ float2 sMl[256];                                // split-0 (m,l)

    const int t    = threadIdx.x;
    const int lane = t & 63;
    const int wave = t >> 6;          // 0..7
    const int sp   = wave >> 2;       // split
    const int w4   = wave & 3;        // wave within split
    const int l31  = lane & 31;
    const int g    = lane >> 5;

    // grid: x = h + 8*b (XCD = h), y = qblock
    const int h  = blockIdx.x & (NHEADS - 1);
    const int b  = blockIdx.x >> 3;
    const int q0 = blockIdx.y * 256;
    const int kBase = sp * (SEQ / 2);

    const size_t rowBase = (size_t)b * SEQ;
    const size_t vBase   = ((size_t)(b * NHEADS + h)) * DK * SEQ;

    _Float16* sK0 = sKall + sp * 2 * 4096;
    _Float16* sV0 = sVall + sp * 2 * 4096;

    // ---- DMA pointers; issue K/V tile 0 immediately ----
    const int subrow = lane >> 3;
    const int schunk = ((lane & 7) ^ subrow) * 8;
    const _Float16* kP[2];
    const _Float16* vP[2];
    #pragma unroll
    for (int j = 0; j < 2; ++j) {
        const int rw = w4 * 16 + j * 8;
        kP[j] = Kf + (rowBase + kBase + rw + subrow) * 512 + h * 64 + schunk;
        vP[j] = Vtf + vBase + (size_t)(rw + subrow) * SEQ + kBase + schunk;
        gload_lds16(kP[j], sK0 + rw * 64);
        gload_lds16(vP[j], sV0 + rw * 64);
        kP[j] += 64 * 512;
        vP[j] += 64;
    }

    // ---- Q fragments direct from global: qf[qt][kc] ----
    half8 qf[2][4];
    #pragma unroll
    for (int qt = 0; qt < 2; ++qt)
        #pragma unroll
        for (int kc = 0; kc < 4; ++kc)
            qf[qt][kc] = *(const half8*)(Qf +
                (rowBase + q0 + w4 * 64 + qt * 32 + l31) * 512 +
                h * 64 + kc * 16 + g * 8);

    const int rs = l31 & 7;   // row-XOR swizzle key for K/V LDS reads

    float m_r = 0.0f;
    f32x16 nbv = {};          // -m_r broadcast; all-zero in the common path
    float l_r[2] = { 0.0f, 0.0f };
    f32x16 of[2][2] = {};     // [qt][dt]

    for (int itp = 0; itp < NIT; itp += 2) {
        #pragma unroll
        for (int cur = 0; cur < 2; ++cur) {     // compile-time cur
            const int it = itp + cur;
            _Float16* sK = sK0 + cur * 4096;
            _Float16* sV = sV0 + cur * 4096;
            __syncthreads();   // drains DMA(it) + frees buf cur^1
            if (it + 1 < NIT) {
                #pragma unroll
                for (int j = 0; j < 2; ++j) {
                    const int rw = w4 * 16 + j * 8;
                    gload_lds16(kP[j], sK0 + (cur ^ 1) * 4096 + rw * 64);
                    gload_lds16(vP[j], sV0 + (cur ^ 1) * 4096 + rw * 64);
                    kP[j] += 64 * 512;
                    vP[j] += 64;
                }
            }

            #pragma unroll
            for (int kt = 0; kt < 2; ++kt) {
                // ---- S^T = K · Q^T : 8 MFMA, K frag shared across qt ----
                f32x16 sf0, sf1;
                __builtin_amdgcn_s_setprio(1);
                #pragma unroll
                for (int kc = 0; kc < 4; ++kc) {
                    const int pos = ((kc * 2 + g) ^ rs) * 8;
                    half8 kf = *(const half8*)&sK[(kt * 32 + l31) * 64 + pos];
                    sf0 = MFMA32(kf, qf[0][kc], kc == 0 ? nbv : sf0);
                    sf1 = MFMA32(kf, qf[1][kc], kc == 0 ? nbv : sf1);
                }
                __builtin_amdgcn_s_setprio(0);

                // ---- softmax in-register; l accumulated on VALU ----
                float lrs0 = 0.0f, lrs1 = 0.0f;
                #pragma unroll
                for (int j2 = 0; j2 < 16; ++j2) {
                    sf0[j2] = EXP2F(sf0[j2]);  lrs0 += sf0[j2];
                    sf1[j2] = EXP2F(sf1[j2]);  lrs1 += sf1[j2];
                }
                l_r[0] += lrs0;
                l_r[1] += lrs1;

                // ---- P^T -> B frags: 8 cvt_pk + 4 permlane per qt ----
                PFu pf0[2], pf1[2];
                #define MKPF(P, PF)                                                  \
                    do {                                                             \
                        unsigned int x1 = cvtpk(P[0], P[1]),  x2 = cvtpk(P[2], P[3]);\
                        unsigned int y1 = cvtpk(P[4], P[5]),  y2 = cvtpk(P[6], P[7]);\
                        PLSWAP(x1, y1); PLSWAP(x2, y2);                              \
                        PF[0].u[0] = x1; PF[0].u[1] = x2;                            \
                        PF[0].u[2] = y1; PF[0].u[3] = y2;                            \
                        unsigned int a1 = cvtpk(P[8], P[9]),  a2 = cvtpk(P[10], P[11]);\
                        unsigned int b1 = cvtpk(P[12], P[13]), b2 = cvtpk(P[14], P[15]);\
                        PLSWAP(a1, b1); PLSWAP(a2, b2);                              \
                        PF[1].u[0] = a1; PF[1].u[1] = a2;                            \
                        PF[1].u[2] = b1; PF[1].u[3] = b2;                            \
                    } while (0)
                MKPF(sf0, pf0);
                MKPF(sf1, pf1);
                #undef MKPF

                // ---- O^T += V^T·P^T (V frag shared across qt) ----
                __builtin_amdgcn_s_setprio(1);
                #pragma unroll
                for (int ks2 = 0; ks2 < 2; ++ks2) {
                    const int ks = kt * 2 + ks2;
                    const int pos = ((ks * 2 + g) ^ rs) * 8;
                    half8 v0 = *(const half8*)&sV[l31 * 64 + pos];
                    half8 v1 = *(const half8*)&sV[(32 + l31) * 64 + pos];
                    of[0][0] = MFMA32(v0, pf0[ks2].h8, of[0][0]);
                    of[0][1] = MFMA32(v1, pf0[ks2].h8, of[0][1]);
                    of[1][0] = MFMA32(v0, pf1[ks2].h8, of[1][0]);
                    of[1][1] = MFMA32(v1, pf1[ks2].h8, of[1][1]);
                }
                __builtin_amdgcn_s_setprio(0);
            }

            // ---- rare re-center: running l too large -> scale down 2^-10 ----
            if (__any(fmaxf(l_r[0], l_r[1]) > 1048576.0f)) {
                const float al = 0.0009765625f;   // 2^-10
                #pragma unroll
                for (int qt = 0; qt < 2; ++qt) {
                    l_r[qt] *= al;
                    #pragma unroll
                    for (int j2 = 0; j2 < 16; ++j2) {
                        of[qt][0][j2] *= al;
                        of[qt][1][j2] *= al;
                    }
                }
                m_r += 10.0f;
                #pragma unroll
                for (int j2 = 0; j2 < 16; ++j2) nbv[j2] = -m_r;
            }
        }
    }

    // ======== in-block flash combine (split 0 -> LDS, split 1 merges) ========
    __syncthreads();   // all LDS reads of sK/sV done; sKall region reusable
    _Float16* sOex = sKall;   // 256 q x 64 d fp16, XOR-swizzled (32 KB exact)

    if (sp == 0) {
        #pragma unroll
        for (int qt = 0; qt < 2; ++qt) {
            const float l = l_r[qt] + __shfl_xor(l_r[qt], 32);
            const float inv = 1.0f / l;
            const int ql = w4 * 64 + qt * 32 + l31;
            #pragma unroll
            for (int dt = 0; dt < 2; ++dt) {
                #pragma unroll
                for (int m4 = 0; m4 < 4; ++m4) {
                    const int d0 = dt * 32 + 8 * m4 + 4 * g;
                    const int s = (d0 >> 2) ^ ((ql & 7) << 1);
                    Pkz z2;
                    z2.h2[0] = __builtin_amdgcn_cvt_pkrtz(of[qt][dt][4 * m4 + 0] * inv,
                                                          of[qt][dt][4 * m4 + 1] * inv);
                    z2.h2[1] = __builtin_amdgcn_cvt_pkrtz(of[qt][dt][4 * m4 + 2] * inv,
                                                          of[qt][dt][4 * m4 + 3] * inv);
                    *(uint2*)&sOex[ql * 64 + s * 4] = z2.u;
                }
            }
            if (lane < 32) sMl[ql] = make_float2(m_r, l);
        }
    }
    __syncthreads();
    if (sp == 1) {
        #pragma unroll
        for (int qt = 0; qt < 2; ++qt) {
            const float lB = l_r[qt] + __shfl_xor(l_r[qt], 32);
            const int ql = w4 * 64 + qt * 32 + l31;
            const float2 mlA = sMl[ql];
            const float m = fmaxf(mlA.x, m_r);
            float wA = EXP2F(mlA.x - m) * mlA.y;
            float wB = EXP2F(m_r - m) * lB;
            const float inv = 1.0f / (wA + wB);
            wA *= inv;
            const float wBn = wB * inv / lB;   // applied to unnormalized of
            const size_t R = rowBase + q0 + ql;
            #pragma unroll
            for (int dt = 0; dt < 2; ++dt) {
                #pragma unroll
                for (int m4 = 0; m4 < 4; ++m4) {
                    const int d0 = dt * 32 + 8 * m4 + 4 * g;
                    const int s = (d0 >> 2) ^ ((ql & 7) << 1);
                    Un4 oa;
                    oa.u = *(const uint2*)&sOex[ql * 64 + s * 4];
                    Pkz z2;
                    z2.h2[0] = __builtin_amdgcn_cvt_pkrtz(
                        wA * (float)oa.h[0] + wBn * of[qt][dt][4 * m4 + 0],
                        wA * (float)oa.h[1] + wBn * of[qt][dt][4 * m4 + 1]);
                    z2.h2[1] = __builtin_amdgcn_cvt_pkrtz(
                        wA * (float)oa.h[2] + wBn * of[qt][dt][4 * m4 + 2],
                        wA * (float)oa.h[3] + wBn * of[qt][dt][4 * m4 + 3]);
                    *(uint2*)(Oh + R * 512 + h * 64 + d0) = z2.u;
                }
            }
        }
    }
}

// ============================================================================
// Output projection, r10: A = Oh (fp16, DMA); W = w_o read directly as fp32,
// converted during reg-staging (prep deleted). 128x64 block, double-buffered.
// ============================================================================
__global__ __launch_bounds__(256)
void gemm_out(const _Float16* __restrict__ Ah, const float* __restrict__ W,
              const float* __restrict__ bias, float* __restrict__ C) {
    __shared__ __align__(16) _Float16 sAh[2][128 * 64];
    __shared__ __align__(16) _Float16 sWh[2][64 * 64];

    const int t    = threadIdx.x;
    const int lane = t & 63, wave = t >> 6;
    const int col  = lane & 15, quad = lane >> 4;
    const int wm   = (wave & 1) * 64, wn = (wave >> 1) * 32;
    const int m0   = blockIdx.y * 128, n0 = blockIdx.x * 64;

    const int subrow = lane >> 3;
    const int schunk = ((lane & 7) ^ subrow) * 8;

    const float* wBase = W + (size_t)(n0 + wave * 16 + subrow) * 512 + schunk;

    float4 wr[2][2];
    #define STAGE_A(K0, BUF)                                                       \
        do {                                                                       \
            _Pragma("unroll")                                                      \
            for (int j = 0; j < 4; ++j) {                                          \
                const int rw = wave * 32 + j * 8;                                  \
                gload_lds16(Ah + (size_t)(m0 + rw + subrow) * 512 + (K0) + schunk, \
                            &sAh[BUF][rw * 64]);                                   \
            }                                                                      \
        } while (0)
    #define LOAD_WO(K0)                                                           \
        do {                                                                       \
            _Pragma("unroll")                                                      \
            for (int j = 0; j < 2; ++j) {                                          \
                const float* s = wBase + (size_t)(j * 8) * 512 + (K0);             \
                wr[j][0] = *(const float4*)s;                                      \
                wr[j][1] = *(const float4*)(s + 4);                                \
            }                                                                      \
        } while (0)
    #define WRITE_WO(BUF)                                                          \
        do {                                                                       \
            _Pragma("unroll")                                                      \
            for (int j = 0; j < 2; ++j) {                                          \
                uint4 p;                                                           \
                p.x = cvtpk(wr[j][0].x, wr[j][0].y);                               \
                p.y = cvtpk(wr[j][0].z, wr[j][0].w);                               \
                p.z = cvtpk(wr[j][1].x, wr[j][1].y);                               \
                p.w = cvtpk(wr[j][1].z, wr[j][1].w);                               \
                *(uint4*)&sWh[BUF][(wave * 16 + j * 8) * 64 + lane * 8] = p;       \
            }                                                                      \
        } while (0)

    f32x4 acc[4][2] = {};

    STAGE_A(0, 0);
    LOAD_WO(0);
    WRITE_WO(0);

    for (int ck = 0; ck < 8; ++ck) {
        const int cur = ck & 1;
        __syncthreads();
        if (ck + 1 < 8) {
            STAGE_A((ck + 1) * 64, cur ^ 1);
            LOAD_WO((ck + 1) * 64);
        }

        #pragma unroll
        for (int kc = 0; kc < 2; ++kc) {
            const int pos = ((kc * 4 + quad) ^ (col & 7)) * 8;
            half8 ahf[4], whf[2];
            #pragma unroll
            for (int mt = 0; mt < 4; ++mt)
                ahf[mt] = *(const half8*)&sAh[cur][(wm + mt * 16 + col) * 64 + pos];
            #pragma unroll
            for (int nt = 0; nt < 2; ++nt)
                whf[nt] = *(const half8*)&sWh[cur][(wn + nt * 16 + col) * 64 + pos];
            #pragma unroll
            for (int mt = 0; mt < 4; ++mt)
                #pragma unroll
                for (int nt = 0; nt < 2; ++nt)
                    acc[mt][nt] = MFMA16(ahf[mt], whf[nt], acc[mt][nt]);
        }

        if (ck + 1 < 8) WRITE_WO(cur ^ 1);
    }

    float bv2[2];
    #pragma unroll
    for (int nt = 0; nt < 2; ++nt) bv2[nt] = bias[n0 + wn + nt * 16 + col];

    #pragma unroll
    for (int mt = 0; mt < 4; ++mt) {
        const int m = m0 + wm + mt * 16 + quad * 4;
        #pragma unroll
        for (int nt = 0; nt < 2; ++nt) {
            const int n = n0 + wn + nt * 16 + col;
            #pragma unroll
            for (int r = 0; r < 4; ++r)
                C[(size_t)(m + r) * 512 + n] = acc[mt][nt][r] + bv2[nt];
        }
    }
}

// ============================================================================
extern "C" void kernel_launch(void* const* d_in, const int* in_sizes, int n_in,
                              void* d_out, int out_size, void* d_ws, size_t ws_size,
                              hipStream_t stream) {
    const float* query = (const float*)d_in[0];
    const float* key   = (const float*)d_in[1];
    const float* value = (const float*)d_in[2];
    const float* w_q   = (const float*)d_in[3];
    const float* b_q   = (const float*)d_in[4];
    const float* w_k   = (const float*)d_in[5];
    const float* b_k   = (const float*)d_in[6];
    const float* w_v   = (const float*)d_in[7];
    const float* b_v   = (const float*)d_in[8];
    const float* w_o   = (const float*)d_in[9];
    const float* b_o   = (const float*)d_in[10];
    float* out = (float*)d_out;

    const size_t plane = (size_t)BATCH * SEQ * D_MODEL;   // 4.19M halves

    _Float16* base = (_Float16*)d_ws;
    _Float16* Oh   = base;                 // attn output (fp16)
    _Float16* Qf   = Oh + plane;
    _Float16* Kf   = Qf + plane;
    _Float16* Vtf  = Kf + plane;

    dim3 blk(256);

    hipLaunchKernelGGL(gemm_qkv, dim3(D_MODEL / 128, BATCH * SEQ / 128, 3), blk, 0, stream,
                       query, key, value,
                       w_q, w_k, w_v,
                       b_q, b_k, b_v, Qf, Kf, Vtf);

    hipLaunchKernelGGL(attn_mfma, dim3(NHEADS * BATCH, SEQ / 256), dim3(512), 0, stream,
                       Qf, Kf, Vtf, Oh);

    hipLaunchKernelGGL(gemm_out, dim3(D_MODEL / 64, BATCH * SEQ / 128), blk, 0, stream,
                       Oh, w_o, b_o, out);
}

// Round 11
// 222.278 us; speedup vs baseline: 3.9613x; 1.0294x over previous
//
#include <hip/hip_runtime.h>
#include <math.h>

#define D_MODEL 512
#define NHEADS 8
#define DK 64
#define BATCH 2
#define SEQ 4096
#define NIT 32          // 2048 keys per split / 64-key tiles
// log2(e)/8 folded into Q projection: scores in log2 domain, softmax uses exp2.
#define ATTN_SCALE 0.18033688011112043f

typedef _Float16 half8 __attribute__((ext_vector_type(8)));
typedef _Float16 half4 __attribute__((ext_vector_type(4)));
typedef __fp16 pkhalf2 __attribute__((ext_vector_type(2)));
typedef float f32x4 __attribute__((ext_vector_type(4)));
typedef float f32x16 __attribute__((ext_vector_type(16)));

union Pk8 { _Float16 h[8]; uint4 u; };
union Pk4 { _Float16 h[4]; uint2 u; };
union Pkz { pkhalf2 h2[2]; uint2 u; };
union Un4 { uint2 u; _Float16 h[4]; };
union PFu { unsigned int u[4]; half8 h8; };

#if __has_builtin(__builtin_amdgcn_exp2f)
#define EXP2F __builtin_amdgcn_exp2f
#else
#define EXP2F exp2f
#endif

#define MFMA16(a, b, c) __builtin_amdgcn_mfma_f32_16x16x32_f16((a), (b), (c), 0, 0, 0)
#define MFMA32(a, b, c) __builtin_amdgcn_mfma_f32_32x32x16_f16((a), (b), (c), 0, 0, 0)

// in-place cross-half lane exchange: x[32..63] <- y_old[0..31], y[0..31] <- x_old[32..63]
#define PLSWAP(x, y) asm volatile("v_permlane32_swap_b32 %0, %1" : "+v"(x), "+v"(y))

__device__ __forceinline__ unsigned int cvtpk(float a, float b) {
    union { pkhalf2 h; unsigned int u; } u_;
    u_.h = __builtin_amdgcn_cvt_pkrtz(a, b);
    return u_.u;
}

__device__ __forceinline__ void gload_lds16(const _Float16* g, _Float16* l) {
    __builtin_amdgcn_global_load_lds(
        (const __attribute__((address_space(1))) void*)g,
        (__attribute__((address_space(3))) void*)l, 16, 0, 0);
}

// ============================================================================
// QKV projection GEMM, r11: 256x256 tile, 512 threads, grid (2,32,3)=192
// blocks (one full round). A re-reads x4 -> x2: fp32 A traffic 200 -> 100 MB.
// Both A and W converted fp32->fp16 during reg-staging (no prep kernel).
// Staging is PHASE-SPLIT to cap register pressure under the 256-VGPR
// launchability limit for 512-thread blocks:
//   barrier -> LOAD_A(next) -> kc0 MFMA -> WRITE_A + LOAD_W(next)
//           -> kc1 MFMA -> WRITE_W
// LDS = 128 KB (sA 256x64 dbuf + sW 256x64 dbuf) -> 1 block/CU, 8 waves.
// ============================================================================
__global__ __launch_bounds__(512)
void gemm_qkv(const float* __restrict__ Aq, const float* __restrict__ Ak,
              const float* __restrict__ Av,
              const float* __restrict__ Wq, const float* __restrict__ Wk,
              const float* __restrict__ Wv,
              const float* __restrict__ bq, const float* __restrict__ bk,
              const float* __restrict__ bv,
              _Float16* __restrict__ Qf, _Float16* __restrict__ Kf,
              _Float16* __restrict__ Vtf) {
    const int z = blockIdx.z;
    const float* A    = z == 0 ? Aq : (z == 1 ? Ak : Av);
    const float* W    = z == 0 ? Wq : (z == 1 ? Wk : Wv);
    const float* bias = z == 0 ? bq : (z == 1 ? bk : bv);

    __shared__ __align__(16) _Float16 sA[2][256 * 64];
    __shared__ __align__(16) _Float16 sW[2][256 * 64];

    const int t    = threadIdx.x;
    const int lane = t & 63, wave = t >> 6;     // wave 0..7
    const int col  = lane & 15, quad = lane >> 4;
    const int wm   = (wave & 3) * 64;           // 4 row-groups of 64
    const int wn   = (wave >> 2) * 128;         // 2 col-groups of 128
    const int m0   = blockIdx.y * 256, n0 = blockIdx.x * 256;

    const int subrow = lane >> 3;
    const int schunk = ((lane & 7) ^ subrow) * 8;

    const float* aBase = A + (size_t)(m0 + wave * 32 + subrow) * 512 + schunk;
    const float* wBase = W + (size_t)(n0 + wave * 32 + subrow) * 512 + schunk;

    float4 ar[4][2], wr[4][2];
    #define LOAD_A(K0)                                                            \
        do {                                                                       \
            _Pragma("unroll")                                                      \
            for (int j = 0; j < 4; ++j) {                                          \
                const float* s = aBase + (size_t)(j * 8) * 512 + (K0);             \
                ar[j][0] = *(const float4*)s;                                      \
                ar[j][1] = *(const float4*)(s + 4);                                \
            }                                                                      \
        } while (0)
    #define LOAD_W(K0)                                                            \
        do {                                                                       \
            _Pragma("unroll")                                                      \
            for (int j = 0; j < 4; ++j) {                                          \
                const float* s = wBase + (size_t)(j * 8) * 512 + (K0);             \
                wr[j][0] = *(const float4*)s;                                      \
                wr[j][1] = *(const float4*)(s + 4);                                \
            }                                                                      \
        } while (0)
    #define WRITE_A(BUF)                                                           \
        do {                                                                       \
            _Pragma("unroll")                                                      \
            for (int j = 0; j < 4; ++j) {                                          \
                uint4 p;                                                           \
                p.x = cvtpk(ar[j][0].x, ar[j][0].y);                               \
                p.y = cvtpk(ar[j][0].z, ar[j][0].w);                               \
                p.z = cvtpk(ar[j][1].x, ar[j][1].y);                               \
                p.w = cvtpk(ar[j][1].z, ar[j][1].w);                               \
                *(uint4*)&sA[BUF][(wave * 32 + j * 8) * 64 + lane * 8] = p;        \
            }                                                                      \
        } while (0)
    #define WRITE_W(BUF)                                                           \
        do {                                                                       \
            _Pragma("unroll")                                                      \
            for (int j = 0; j < 4; ++j) {                                          \
                uint4 q;                                                           \
                q.x = cvtpk(wr[j][0].x, wr[j][0].y);                               \
                q.y = cvtpk(wr[j][0].z, wr[j][0].w);                               \
                q.z = cvtpk(wr[j][1].x, wr[j][1].y);                               \
                q.w = cvtpk(wr[j][1].z, wr[j][1].w);                               \
                *(uint4*)&sW[BUF][(wave * 32 + j * 8) * 64 + lane * 8] = q;        \
            }                                                                      \
        } while (0)

    f32x4 acc[4][8] = {};

    LOAD_A(0);
    LOAD_W(0);
    WRITE_A(0);
    WRITE_W(0);

    for (int ck = 0; ck < 8; ++ck) {
        const int cur = ck & 1;
        __syncthreads();
        if (ck + 1 < 8) LOAD_A((ck + 1) * 64);

        // ---- kc = 0 ----
        {
            const int pos = (quad ^ (col & 7)) * 8;
            half8 af[4], wf[8];
            #pragma unroll
            for (int mt = 0; mt < 4; ++mt)
                af[mt] = *(const half8*)&sA[cur][(wm + mt * 16 + col) * 64 + pos];
            #pragma unroll
            for (int nt = 0; nt < 8; ++nt)
                wf[nt] = *(const half8*)&sW[cur][(wn + nt * 16 + col) * 64 + pos];
            #pragma unroll
            for (int mt = 0; mt < 4; ++mt)
                #pragma unroll
                for (int nt = 0; nt < 8; ++nt)
                    acc[mt][nt] = MFMA16(af[mt], wf[nt], acc[mt][nt]);
        }

        if (ck + 1 < 8) {
            WRITE_A(cur ^ 1);
            LOAD_W((ck + 1) * 64);
        }

        // ---- kc = 1 ----
        {
            const int pos = ((4 + quad) ^ (col & 7)) * 8;
            half8 af[4], wf[8];
            #pragma unroll
            for (int mt = 0; mt < 4; ++mt)
                af[mt] = *(const half8*)&sA[cur][(wm + mt * 16 + col) * 64 + pos];
            #pragma unroll
            for (int nt = 0; nt < 8; ++nt)
                wf[nt] = *(const half8*)&sW[cur][(wn + nt * 16 + col) * 64 + pos];
            #pragma unroll
            for (int mt = 0; mt < 4; ++mt)
                #pragma unroll
                for (int nt = 0; nt < 8; ++nt)
                    acc[mt][nt] = MFMA16(af[mt], wf[nt], acc[mt][nt]);
        }

        if (ck + 1 < 8) WRITE_W(cur ^ 1);
    }

    float bv8[8];
    #pragma unroll
    for (int nt = 0; nt < 8; ++nt) bv8[nt] = bias[n0 + wn + nt * 16 + col];

    if (z < 2) {
        _Float16* Out = z == 0 ? Qf : Kf;
        const float alpha = z == 0 ? ATTN_SCALE : 1.0f;
        #pragma unroll
        for (int mt = 0; mt < 4; ++mt) {
            const int m = m0 + wm + mt * 16 + quad * 4;
            #pragma unroll
            for (int nt = 0; nt < 8; ++nt) {
                const int n = n0 + wn + nt * 16 + col;
                #pragma unroll
                for (int r = 0; r < 4; ++r)
                    Out[(size_t)(m + r) * 512 + n] = (_Float16)((acc[mt][nt][r] + bv8[nt]) * alpha);
            }
        }
    } else {
        #pragma unroll
        for (int mt = 0; mt < 4; ++mt) {
            const int m = m0 + wm + mt * 16 + quad * 4;
            const int b = m >> 12, s = m & (SEQ - 1);
            #pragma unroll
            for (int nt = 0; nt < 8; ++nt) {
                const int n = n0 + wn + nt * 16 + col;
                const int hh = n >> 6, d = n & (DK - 1);
                Pk4 p;
                #pragma unroll
                for (int r = 0; r < 4; ++r)
                    p.h[r] = (_Float16)(acc[mt][nt][r] + bv8[nt]);
                *(uint2*)&Vtf[((size_t)((b * NHEADS + hh) * DK + d)) * SEQ + s] = p.u;
            }
        }
    }
}

// ============================================================================
// Flash attention (r9 form, unchanged): both K-splits in one 512-thread block,
// in-block flash merge, 64 q/wave, register P via permlane, 32 MFMA32/wave-iter.
// ============================================================================
__global__ __launch_bounds__(512)
void attn_mfma(const _Float16* __restrict__ Qf, const _Float16* __restrict__ Kf,
               const _Float16* __restrict__ Vtf, _Float16* __restrict__ Oh) {
    __shared__ __align__(16) _Float16 sKall[2 * 2 * 64 * 64];  // [sp][cur] 32 KB
    __shared__ __align__(16) _Float16 sVall[2 * 2 * 64 * 64];  // [sp][cur] 32 KB
    __shared__ float2 sMl[256];                                // split-0 (m,l)

    const int t    = threadIdx.x;
    const int lane = t & 63;
    const int wave = t >> 6;          // 0..7
    const int sp   = wave >> 2;       // split
    const int w4   = wave & 3;        // wave within split
    const int l31  = lane & 31;
    const int g    = lane >> 5;

    // grid: x = h + 8*b (XCD = h), y = qblock
    const int h  = blockIdx.x & (NHEADS - 1);
    const int b  = blockIdx.x >> 3;
    const int q0 = blockIdx.y * 256;
    const int kBase = sp * (SEQ / 2);

    const size_t rowBase = (size_t)b * SEQ;
    const size_t vBase   = ((size_t)(b * NHEADS + h)) * DK * SEQ;

    _Float16* sK0 = sKall + sp * 2 * 4096;
    _Float16* sV0 = sVall + sp * 2 * 4096;

    // ---- DMA pointers; issue K/V tile 0 immediately ----
    const int subrow = lane >> 3;
    const int schunk = ((lane & 7) ^ subrow) * 8;
    const _Float16* kP[2];
    const _Float16* vP[2];
    #pragma unroll
    for (int j = 0; j < 2; ++j) {
        const int rw = w4 * 16 + j * 8;
        kP[j] = Kf + (rowBase + kBase + rw + subrow) * 512 + h * 64 + schunk;
        vP[j] = Vtf + vBase + (size_t)(rw + subrow) * SEQ + kBase + schunk;
        gload_lds16(kP[j], sK0 + rw * 64);
        gload_lds16(vP[j], sV0 + rw * 64);
        kP[j] += 64 * 512;
        vP[j] += 64;
    }

    // ---- Q fragments direct from global: qf[qt][kc] ----
    half8 qf[2][4];
    #pragma unroll
    for (int qt = 0; qt < 2; ++qt)
        #pragma unroll
        for (int kc = 0; kc < 4; ++kc)
            qf[qt][kc] = *(const half8*)(Qf +
                (rowBase + q0 + w4 * 64 + qt * 32 + l31) * 512 +
                h * 64 + kc * 16 + g * 8);

    const int rs = l31 & 7;   // row-XOR swizzle key for K/V LDS reads

    float m_r = 0.0f;
    f32x16 nbv = {};          // -m_r broadcast; all-zero in the common path
    float l_r[2] = { 0.0f, 0.0f };
    f32x16 of[2][2] = {};     // [qt][dt]

    for (int itp = 0; itp < NIT; itp += 2) {
        #pragma unroll
        for (int cur = 0; cur < 2; ++cur) {     // compile-time cur
            const int it = itp + cur;
            _Float16* sK = sK0 + cur * 4096;
            _Float16* sV = sV0 + cur * 4096;
            __syncthreads();   // drains DMA(it) + frees buf cur^1
            if (it + 1 < NIT) {
                #pragma unroll
                for (int j = 0; j < 2; ++j) {
                    const int rw = w4 * 16 + j * 8;
                    gload_lds16(kP[j], sK0 + (cur ^ 1) * 4096 + rw * 64);
                    gload_lds16(vP[j], sV0 + (cur ^ 1) * 4096 + rw * 64);
                    kP[j] += 64 * 512;
                    vP[j] += 64;
                }
            }

            #pragma unroll
            for (int kt = 0; kt < 2; ++kt) {
                // ---- S^T = K · Q^T : 8 MFMA, K frag shared across qt ----
                f32x16 sf0, sf1;
                __builtin_amdgcn_s_setprio(1);
                #pragma unroll
                for (int kc = 0; kc < 4; ++kc) {
                    const int pos = ((kc * 2 + g) ^ rs) * 8;
                    half8 kf = *(const half8*)&sK[(kt * 32 + l31) * 64 + pos];
                    sf0 = MFMA32(kf, qf[0][kc], kc == 0 ? nbv : sf0);
                    sf1 = MFMA32(kf, qf[1][kc], kc == 0 ? nbv : sf1);
                }
                __builtin_amdgcn_s_setprio(0);

                // ---- softmax in-register; l accumulated on VALU ----
                float lrs0 = 0.0f, lrs1 = 0.0f;
                #pragma unroll
                for (int j2 = 0; j2 < 16; ++j2) {
                    sf0[j2] = EXP2F(sf0[j2]);  lrs0 += sf0[j2];
                    sf1[j2] = EXP2F(sf1[j2]);  lrs1 += sf1[j2];
                }
                l_r[0] += lrs0;
                l_r[1] += lrs1;

                // ---- P^T -> B frags: 8 cvt_pk + 4 permlane per qt ----
                PFu pf0[2], pf1[2];
                #define MKPF(P, PF)                                                  \
                    do {                                                             \
                        unsigned int x1 = cvtpk(P[0], P[1]),  x2 = cvtpk(P[2], P[3]);\
                        unsigned int y1 = cvtpk(P[4], P[5]),  y2 = cvtpk(P[6], P[7]);\
                        PLSWAP(x1, y1); PLSWAP(x2, y2);                              \
                        PF[0].u[0] = x1; PF[0].u[1] = x2;                            \
                        PF[0].u[2] = y1; PF[0].u[3] = y2;                            \
                        unsigned int a1 = cvtpk(P[8], P[9]),  a2 = cvtpk(P[10], P[11]);\
                        unsigned int b1 = cvtpk(P[12], P[13]), b2 = cvtpk(P[14], P[15]);\
                        PLSWAP(a1, b1); PLSWAP(a2, b2);                              \
                        PF[1].u[0] = a1; PF[1].u[1] = a2;                            \
                        PF[1].u[2] = b1; PF[1].u[3] = b2;                            \
                    } while (0)
                MKPF(sf0, pf0);
                MKPF(sf1, pf1);
                #undef MKPF

                // ---- O^T += V^T·P^T (V frag shared across qt) ----
                __builtin_amdgcn_s_setprio(1);
                #pragma unroll
                for (int ks2 = 0; ks2 < 2; ++ks2) {
                    const int ks = kt * 2 + ks2;
                    const int pos = ((ks * 2 + g) ^ rs) * 8;
                    half8 v0 = *(const half8*)&sV[l31 * 64 + pos];
                    half8 v1 = *(const half8*)&sV[(32 + l31) * 64 + pos];
                    of[0][0] = MFMA32(v0, pf0[ks2].h8, of[0][0]);
                    of[0][1] = MFMA32(v1, pf0[ks2].h8, of[0][1]);
                    of[1][0] = MFMA32(v0, pf1[ks2].h8, of[1][0]);
                    of[1][1] = MFMA32(v1, pf1[ks2].h8, of[1][1]);
                }
                __builtin_amdgcn_s_setprio(0);
            }

            // ---- rare re-center: running l too large -> scale down 2^-10 ----
            if (__any(fmaxf(l_r[0], l_r[1]) > 1048576.0f)) {
                const float al = 0.0009765625f;   // 2^-10
                #pragma unroll
                for (int qt = 0; qt < 2; ++qt) {
                    l_r[qt] *= al;
                    #pragma unroll
                    for (int j2 = 0; j2 < 16; ++j2) {
                        of[qt][0][j2] *= al;
                        of[qt][1][j2] *= al;
                    }
                }
                m_r += 10.0f;
                #pragma unroll
                for (int j2 = 0; j2 < 16; ++j2) nbv[j2] = -m_r;
            }
        }
    }

    // ======== in-block flash combine (split 0 -> LDS, split 1 merges) ========
    __syncthreads();   // all LDS reads of sK/sV done; sKall region reusable
    _Float16* sOex = sKall;   // 256 q x 64 d fp16, XOR-swizzled (32 KB exact)

    if (sp == 0) {
        #pragma unroll
        for (int qt = 0; qt < 2; ++qt) {
            const float l = l_r[qt] + __shfl_xor(l_r[qt], 32);
            const float inv = 1.0f / l;
            const int ql = w4 * 64 + qt * 32 + l31;
            #pragma unroll
            for (int dt = 0; dt < 2; ++dt) {
                #pragma unroll
                for (int m4 = 0; m4 < 4; ++m4) {
                    const int d0 = dt * 32 + 8 * m4 + 4 * g;
                    const int s = (d0 >> 2) ^ ((ql & 7) << 1);
                    Pkz z2;
                    z2.h2[0] = __builtin_amdgcn_cvt_pkrtz(of[qt][dt][4 * m4 + 0] * inv,
                                                          of[qt][dt][4 * m4 + 1] * inv);
                    z2.h2[1] = __builtin_amdgcn_cvt_pkrtz(of[qt][dt][4 * m4 + 2] * inv,
                                                          of[qt][dt][4 * m4 + 3] * inv);
                    *(uint2*)&sOex[ql * 64 + s * 4] = z2.u;
                }
            }
            if (lane < 32) sMl[ql] = make_float2(m_r, l);
        }
    }
    __syncthreads();
    if (sp == 1) {
        #pragma unroll
        for (int qt = 0; qt < 2; ++qt) {
            const float lB = l_r[qt] + __shfl_xor(l_r[qt], 32);
            const int ql = w4 * 64 + qt * 32 + l31;
            const float2 mlA = sMl[ql];
            const float m = fmaxf(mlA.x, m_r);
            float wA = EXP2F(mlA.x - m) * mlA.y;
            float wB = EXP2F(m_r - m) * lB;
            const float inv = 1.0f / (wA + wB);
            wA *= inv;
            const float wBn = wB * inv / lB;   // applied to unnormalized of
            const size_t R = rowBase + q0 + ql;
            #pragma unroll
            for (int dt = 0; dt < 2; ++dt) {
                #pragma unroll
                for (int m4 = 0; m4 < 4; ++m4) {
                    const int d0 = dt * 32 + 8 * m4 + 4 * g;
                    const int s = (d0 >> 2) ^ ((ql & 7) << 1);
                    Un4 oa;
                    oa.u = *(const uint2*)&sOex[ql * 64 + s * 4];
                    Pkz z2;
                    z2.h2[0] = __builtin_amdgcn_cvt_pkrtz(
                        wA * (float)oa.h[0] + wBn * of[qt][dt][4 * m4 + 0],
                        wA * (float)oa.h[1] + wBn * of[qt][dt][4 * m4 + 1]);
                    z2.h2[1] = __builtin_amdgcn_cvt_pkrtz(
                        wA * (float)oa.h[2] + wBn * of[qt][dt][4 * m4 + 2],
                        wA * (float)oa.h[3] + wBn * of[qt][dt][4 * m4 + 3]);
                    *(uint2*)(Oh + R * 512 + h * 64 + d0) = z2.u;
                }
            }
        }
    }
}

// ============================================================================
// Output projection, r11: 128x128 tile (N 64 -> 128): Oh re-reads x8 -> x4
// (64 -> 32 MB). A = Oh fp16 via DMA; W = w_o fp32 converted during
// reg-staging. LDS 64 KB -> 2 blocks/CU, grid (4,64)=256 blocks.
// ============================================================================
__global__ __launch_bounds__(256)
void gemm_out(const _Float16* __restrict__ Ah, const float* __restrict__ W,
              const float* __restrict__ bias, float* __restrict__ C) {
    __shared__ __align__(16) _Float16 sAh[2][128 * 64];
    __shared__ __align__(16) _Float16 sWh[2][128 * 64];

    const int t    = threadIdx.x;
    const int lane = t & 63, wave = t >> 6;
    const int col  = lane & 15, quad = lane >> 4;
    const int wm   = (wave & 1) * 64, wn = (wave >> 1) * 64;
    const int m0   = blockIdx.y * 128, n0 = blockIdx.x * 128;

    const int subrow = lane >> 3;
    const int schunk = ((lane & 7) ^ subrow) * 8;

    const float* wBase = W + (size_t)(n0 + wave * 32 + subrow) * 512 + schunk;

    float4 wr[4][2];
    #define STAGE_A(K0, BUF)                                                       \
        do {                                                                       \
            _Pragma("unroll")                                                      \
            for (int j = 0; j < 4; ++j) {                                          \
                const int rw = wave * 32 + j * 8;                                  \
                gload_lds16(Ah + (size_t)(m0 + rw + subrow) * 512 + (K0) + schunk, \
                            &sAh[BUF][rw * 64]);                                   \
            }                                                                      \
        } while (0)
    #define LOAD_WO(K0)                                                           \
        do {                                                                       \
            _Pragma("unroll")                                                      \
            for (int j = 0; j < 4; ++j) {                                          \
                const float* s = wBase + (size_t)(j * 8) * 512 + (K0);             \
                wr[j][0] = *(const float4*)s;                                      \
                wr[j][1] = *(const float4*)(s + 4);                                \
            }                                                                      \
        } while (0)
    #define WRITE_WO(BUF)                                                          \
        do {                                                                       \
            _Pragma("unroll")                                                      \
            for (int j = 0; j < 4; ++j) {                                          \
                uint4 p;                                                           \
                p.x = cvtpk(wr[j][0].x, wr[j][0].y);                               \
                p.y = cvtpk(wr[j][0].z, wr[j][0].w);                               \
                p.z = cvtpk(wr[j][1].x, wr[j][1].y);                               \
                p.w = cvtpk(wr[j][1].z, wr[j][1].w);                               \
                *(uint4*)&sWh[BUF][(wave * 32 + j * 8) * 64 + lane * 8] = p;       \
            }                                                                      \
        } while (0)

    f32x4 acc[4][4] = {};

    STAGE_A(0, 0);
    LOAD_WO(0);
    WRITE_WO(0);

    for (int ck = 0; ck < 8; ++ck) {
        const int cur = ck & 1;
        __syncthreads();
        if (ck + 1 < 8) {
            STAGE_A((ck + 1) * 64, cur ^ 1);
            LOAD_WO((ck + 1) * 64);
        }

        #pragma unroll
        for (int kc = 0; kc < 2; ++kc) {
            const int pos = ((kc * 4 + quad) ^ (col & 7)) * 8;
            half8 ahf[4], whf[4];
            #pragma unroll
            for (int mt = 0; mt < 4; ++mt)
                ahf[mt] = *(const half8*)&sAh[cur][(wm + mt * 16 + col) * 64 + pos];
            #pragma unroll
            for (int nt = 0; nt < 4; ++nt)
                whf[nt] = *(const half8*)&sWh[cur][(wn + nt * 16 + col) * 64 + pos];
            #pragma unroll
            for (int mt = 0; mt < 4; ++mt)
                #pragma unroll
                for (int nt = 0; nt < 4; ++nt)
                    acc[mt][nt] = MFMA16(ahf[mt], whf[nt], acc[mt][nt]);
        }

        if (ck + 1 < 8) WRITE_WO(cur ^ 1);
    }

    float bv4[4];
    #pragma unroll
    for (int nt = 0; nt < 4; ++nt) bv4[nt] = bias[n0 + wn + nt * 16 + col];

    #pragma unroll
    for (int mt = 0; mt < 4; ++mt) {
        const int m = m0 + wm + mt * 16 + quad * 4;
        #pragma unroll
        for (int nt = 0; nt < 4; ++nt) {
            const int n = n0 + wn + nt * 16 + col;
            #pragma unroll
            for (int r = 0; r < 4; ++r)
                C[(size_t)(m + r) * 512 + n] = acc[mt][nt][r] + bv4[nt];
        }
    }
}

// ============================================================================
extern "C" void kernel_launch(void* const* d_in, const int* in_sizes, int n_in,
                              void* d_out, int out_size, void* d_ws, size_t ws_size,
                              hipStream_t stream) {
    const float* query = (const float*)d_in[0];
    const float* key   = (const float*)d_in[1];
    const float* value = (const float*)d_in[2];
    const float* w_q   = (const float*)d_in[3];
    const float* b_q   = (const float*)d_in[4];
    const float* w_k   = (const float*)d_in[5];
    const float* b_k   = (const float*)d_in[6];
    const float* w_v   = (const float*)d_in[7];
    const float* b_v   = (const float*)d_in[8];
    const float* w_o   = (const float*)d_in[9];
    const float* b_o   = (const float*)d_in[10];
    float* out = (float*)d_out;

    const size_t plane = (size_t)BATCH * SEQ * D_MODEL;   // 4.19M halves

    _Float16* base = (_Float16*)d_ws;
    _Float16* Oh   = base;                 // attn output (fp16)
    _Float16* Qf   = Oh + plane;
    _Float16* Kf   = Qf + plane;
    _Float16* Vtf  = Kf + plane;

    hipLaunchKernelGGL(gemm_qkv, dim3(D_MODEL / 256, BATCH * SEQ / 256, 3), dim3(512), 0, stream,
                       query, key, value,
                       w_q, w_k, w_v,
                       b_q, b_k, b_v, Qf, Kf, Vtf);

    hipLaunchKernelGGL(attn_mfma, dim3(NHEADS * BATCH, SEQ / 256), dim3(512), 0, stream,
                       Qf, Kf, Vtf, Oh);

    hipLaunchKernelGGL(gemm_out, dim3(D_MODEL / 128, BATCH * SEQ / 128), dim3(256), 0, stream,
                       Oh, w_o, b_o, out);
}